// Round 4
// baseline (1219.839 us; speedup 1.0000x reference)
//
#include <hip/hip_runtime.h>
#include <cstdint>
#include <cstddef>

#define D_IN   128
#define D_HID  32
#define D_OUT  32
#define NEG_SLOPE 0.2f
#define EPS_F  1e-16f
#define SCAN_CHUNK 1024   // elements per block in scan phase A (256 thr x 4)

// two-level binning params
#define BKT2_SHIFT 12     // 4096 nodes per bucket
#define KBUKMAX 32        // supports N <= 131072
#define CAPB 128          // LDS entries per bucket (flush chunk = 64)
#define BKCAP 73728       // entries per bucket region (mean ~69.7K, +15 sigma)
#define TCAP 16384        // tail entries per bucket

// ---------------------------------------------------------------------------
// edge_index may arrive as int32 or int64. Detect on device: values < 2^17,
// so int64 => every odd int32 word (high half, LE) of the first 64 pairs is 0.
// ---------------------------------------------------------------------------
__global__ void detect_kernel(const int* __restrict__ ei, long long E, int* __restrict__ flag) {
    const int t = threadIdx.x;                     // 64 threads
    long long n = E < 64 ? E : 64;
    int bad = (t < n && ei[2 * t + 1] != 0) ? 1 : 0;
    unsigned long long mask = __ballot(bad);
    if (t == 0) *flag = (mask == 0ULL) ? 1 : 0;
}

__device__ __forceinline__ int edge_val(const int* __restrict__ ei, long long idx, int is64) {
    return is64 ? ei[idx * 2] : ei[idx];
}

// ---------------------------------------------------------------------------
// Pass A: fused degree-count + LDS-staged binning. Each 64-entry (256B) chunk
// of a bucket's global region is written whole by ONE wave -> dense writeback,
// no 16x line amplification (R3 lesson: cross-XCD partial lines stay dirty).
// ---------------------------------------------------------------------------
__global__ __launch_bounds__(256) void bin_a_kernel(
        const int* __restrict__ ei, const int* __restrict__ flag,
        long long E, long long E2,
        int* __restrict__ cnt, int* __restrict__ chunkcur, int* __restrict__ tailcur,
        unsigned* __restrict__ binsg, unsigned* __restrict__ tails, int K2) {
    __shared__ unsigned binbuf[KBUKMAX][CAPB];     // 16 KB
    __shared__ int bincnt[KBUKMAX];
    const int is64 = *flag;
    const int t = threadIdx.x;
    const int lane = t & 63, wid = t >> 6;
    if (t < K2) bincnt[t] = 0;
    __syncthreads();
    const long long step = (long long)gridDim.x * 1024;
    for (long long rb = (long long)blockIdx.x * 1024; rb < E2; rb += step) {
        // ---- insert up to 1024 edges (4 per thread, coalesced) ----
        #pragma unroll
        for (int k = 0; k < 4; ++k) {
            long long e = rb + k * 256 + t;
            if (e < E2) {
                int s, d;
                if (e < E) { s = edge_val(ei, e, is64); d = edge_val(ei, E + e, is64); }
                else       { s = d = (int)(e - E); }
                atomicAdd(&cnt[d], 1);
                int b = d >> BKT2_SHIFT;
                unsigned val = (unsigned)s | ((unsigned)(d & 4095) << 17);
                int pos = atomicAdd(&bincnt[b], 1);
                if (pos < CAPB) {
                    binbuf[b][pos] = val;
                } else {                            // rare overflow slow path
                    int ti = atomicAdd(&tailcur[b], 1);
                    if (ti < TCAP) tails[(long long)b * TCAP + ti] = val;
                }
            }
        }
        __syncthreads();
        // ---- flush full 64-entry chunks; compact leftovers to front ----
        for (int b = wid; b < K2; b += 4) {
            int n = bincnt[b]; if (n > CAPB) n = CAPB;
            int nch = n >> 6;
            for (int c = 0; c < nch; ++c) {
                int cidx = 0;
                if (lane == 0) cidx = atomicAdd(&chunkcur[b], 1);
                cidx = __shfl(cidx, 0);
                if (cidx < BKCAP / 64)
                    binsg[(long long)b * BKCAP + (long long)cidx * 64 + lane] = binbuf[b][c * 64 + lane];
            }
            int left = n & 63;
            unsigned tmp = 0;
            if (lane < left) tmp = binbuf[b][nch * 64 + lane];
            if (lane < left) binbuf[b][lane] = tmp;
            if (lane == 0) bincnt[b] = left;
        }
        __syncthreads();
    }
    // ---- final: leftover (<64 per bucket) to tails, wave-contiguous ----
    for (int b = wid; b < K2; b += 4) {
        int n = bincnt[b]; if (n > CAPB) n = CAPB;
        int tb = 0;
        if (lane == 0) tb = atomicAdd(&tailcur[b], n);
        tb = __shfl(tb, 0);
        if (lane < n && tb + lane < TCAP)
            tails[(long long)b * TCAP + tb + lane] = binbuf[b][lane];
    }
}

// ---------------- hierarchical scan: cnt[N] -> rowptr/dis -----------------
__global__ void scan_a_kernel(const int* __restrict__ cnt, int* __restrict__ rowptr,
                              float* __restrict__ dis, int* __restrict__ blocksum, int N) {
    __shared__ int wsum[4];                        // 256 threads = 4 waves
    const int t = threadIdx.x;
    const int base = blockIdx.x * SCAN_CHUNK;
    const int i0 = base + t * 4;
    int v[4];
    int s = 0;
    if (i0 + 4 <= N) {
        int4 c4 = *(const int4*)(cnt + i0);
        v[0] = c4.x; v[1] = c4.y; v[2] = c4.z; v[3] = c4.w;
        #pragma unroll
        for (int k = 0; k < 4; ++k) {
            s += v[k];
            dis[i0 + k] = rsqrtf((float)v[k]);     // deg >= 1 (self-loop)
        }
    } else {
        #pragma unroll
        for (int k = 0; k < 4; ++k) {
            int idx = i0 + k;
            int c = (idx < N) ? cnt[idx] : 0;
            v[k] = c; s += c;
            if (idx < N) dis[idx] = rsqrtf((float)c);
        }
    }
    const int lane = t & 63, wid = t >> 6;
    int incl = s;
    #pragma unroll
    for (int d = 1; d < 64; d <<= 1) {
        int u = __shfl_up(incl, d);
        if (lane >= d) incl += u;
    }
    if (lane == 63) wsum[wid] = incl;
    __syncthreads();
    int woff = 0;
    for (int w = 0; w < wid; ++w) woff += wsum[w];
    int excl = woff + incl - s;
    #pragma unroll
    for (int k = 0; k < 4; ++k) {
        int idx = i0 + k;
        if (idx < N) rowptr[idx] = excl;
        excl += v[k];
    }
    if (t == 255) blocksum[blockIdx.x] = woff + incl;
}

__global__ void scan_b_kernel(int* __restrict__ blocksum, int* __restrict__ rowptr,
                              int NB, int N, int total) {
    __shared__ int wsum[16];
    __shared__ int carry_s;
    const int t = threadIdx.x;                     // 1024
    const int lane = t & 63, wid = t >> 6;
    if (t == 0) carry_s = 0;
    __syncthreads();
    for (int start = 0; start < NB; start += 1024) {
        int idx = start + t;
        int v = (idx < NB) ? blocksum[idx] : 0;
        int incl = v;
        #pragma unroll
        for (int d = 1; d < 64; d <<= 1) {
            int u = __shfl_up(incl, d);
            if (lane >= d) incl += u;
        }
        if (lane == 63) wsum[wid] = incl;
        __syncthreads();
        int woff = 0;
        for (int w = 0; w < wid; ++w) woff += wsum[w];
        int carry = carry_s;
        __syncthreads();
        if (idx < NB) blocksum[idx] = carry + woff + incl - v;
        if (t == 1023) carry_s = carry + woff + incl;
        __syncthreads();
    }
    if (t == 0) rowptr[N] = total;
}

__global__ void scan_c_kernel(int* __restrict__ rowptr, const int* __restrict__ blocksum, int N) {
    int idx = blockIdx.x * blockDim.x + threadIdx.x;
    if (idx < N) rowptr[idx] += blocksum[idx / SCAN_CHUNK];
}

// ---------------------------------------------------------------------------
// Pass B: one block per bucket. Cursors for the bucket's 4096 nodes live in
// LDS; the CSR window (~280 KB) is written by this single CU -> lines go
// fully dirty in one L2 -> dense writeback.
// ---------------------------------------------------------------------------
__global__ __launch_bounds__(1024) void fill3_kernel(
        const unsigned* __restrict__ binsg, const unsigned* __restrict__ tails,
        const int* __restrict__ chunkcur, const int* __restrict__ tailcur,
        const int* __restrict__ rowptr, int* __restrict__ csr_src, int N, int K2) {
    __shared__ int lcur[1 << BKT2_SHIFT];          // 16 KB
    const int b = blockIdx.x;
    const int nbase = b << BKT2_SHIFT;
    const int nn = min(1 << BKT2_SHIFT, N - nbase);
    for (int i = threadIdx.x; i < nn; i += 1024) lcur[i] = rowptr[nbase + i];
    __syncthreads();
    int nent = min(chunkcur[b], BKCAP / 64) * 64;
    const unsigned* bp = binsg + (long long)b * BKCAP;
    for (int i = threadIdx.x; i < nent; i += 1024) {
        unsigned u = bp[i];
        int pos = atomicAdd(&lcur[u >> 17], 1);
        csr_src[pos] = (int)(u & 0x1FFFFu);
    }
    int nt = min(tailcur[b], TCAP);
    const unsigned* tp = tails + (long long)b * TCAP;
    for (int i = threadIdx.x; i < nt; i += 1024) {
        unsigned u = tp[i];
        int pos = atomicAdd(&lcur[u >> 17], 1);
        csr_src[pos] = (int)(u & 0x1FFFFu);
    }
}

// hws[i][:] = dis[i] * (x[i] @ W1)      (pre-scaled so GCN gather needs no dis[src])
__global__ void gemm1_kernel(const float* __restrict__ x, const float* __restrict__ W1,
                             const float* __restrict__ dis, float* __restrict__ hws, int N) {
    __shared__ float sW[D_IN * D_HID];      // 16 KB
    __shared__ float sx[8][D_IN];           // 4 KB
    const int t = threadIdx.x;              // 256
    const int c = t & 31, r = t >> 5;
    for (int i = t; i < D_IN * D_HID; i += 256) sW[i] = W1[i];
    for (long long base = (long long)blockIdx.x * 8; base < N; base += (long long)gridDim.x * 8) {
        __syncthreads();
        if (base + 8 <= N) {
            const float4* xp = (const float4*)(x + base * D_IN);
            float4 v = xp[t];
            sx[t >> 5][(t & 31) * 4 + 0] = v.x;
            sx[t >> 5][(t & 31) * 4 + 1] = v.y;
            sx[t >> 5][(t & 31) * 4 + 2] = v.z;
            sx[t >> 5][(t & 31) * 4 + 3] = v.w;
        } else {
            long long nrem = (N - base) * D_IN;
            for (int i = t; i < nrem; i += 256) sx[i >> 7][i & 127] = x[base * D_IN + i];
        }
        __syncthreads();
        long long row = base + r;
        if (row < N) {
            float acc = 0.0f;
            #pragma unroll 16
            for (int k = 0; k < D_IN; ++k) acc = fmaf(sx[r][k], sW[k * D_HID + c], acc);
            hws[row * D_HID + c] = acc * dis[row];
        }
    }
}

// GCN aggregate + bias + ReLU
__global__ void gcn_agg_kernel(const int* __restrict__ rowptr, const int* __restrict__ csr_src,
                               const float* __restrict__ hws, const float* __restrict__ dis,
                               const float* __restrict__ b1, float* __restrict__ h1, int N) {
    const int lane = threadIdx.x & 63;
    const int c = lane & 31, half = lane >> 5;
    const int wib = threadIdx.x >> 6;       // 4 waves / block
    for (int i = blockIdx.x * 4 + wib; i < N; i += gridDim.x * 4) {
        const int b = rowptr[i], e = rowptr[i + 1];
        float acc = 0.0f;
        for (int j = b + half; j < e; j += 2) {
            int s = csr_src[j];
            acc += hws[(long long)s * D_HID + c];
        }
        acc += __shfl_xor(acc, 32);
        if (half == 0) {
            float v = dis[i] * acc + b1[c];
            h1[(long long)i * D_HID + c] = v > 0.0f ? v : 0.0f;
        }
    }
}

// g = h1 @ W2 ; a_s = g @ att_src ; a_d = g @ att_dst
__global__ void gemm2_kernel(const float* __restrict__ h1, const float* __restrict__ W2,
                             const float* __restrict__ att_s, const float* __restrict__ att_d,
                             float* __restrict__ g, float* __restrict__ a_s, float* __restrict__ a_d,
                             int N) {
    __shared__ float sW[D_HID * D_OUT];     // 4 KB
    __shared__ float sas[D_OUT], sad[D_OUT];
    __shared__ float sh[8][D_HID];          // 1 KB
    const int t = threadIdx.x;              // 256
    const int c = t & 31, r = t >> 5;
    for (int i = t; i < D_HID * D_OUT; i += 256) sW[i] = W2[i];
    if (t < D_OUT) { sas[t] = att_s[t]; sad[t] = att_d[t]; }
    for (long long base = (long long)blockIdx.x * 8; base < N; base += (long long)gridDim.x * 8) {
        __syncthreads();
        if (base * D_HID + t < (long long)N * D_HID) sh[r][c] = h1[base * D_HID + t];
        __syncthreads();
        long long row = base + r;
        if (row < N) {
            float gv = 0.0f;
            #pragma unroll
            for (int k = 0; k < D_HID; ++k) gv = fmaf(sh[r][k], sW[k * D_OUT + c], gv);
            g[row * D_OUT + c] = gv;
            float ps = gv * sas[c];
            float pd = gv * sad[c];
            #pragma unroll
            for (int d = 16; d >= 1; d >>= 1) {
                ps += __shfl_xor(ps, d);
                pd += __shfl_xor(pd, d);
            }
            if (c == 0) { a_s[row] = ps; a_d[row] = pd; }
        }
    }
}

// GAT aggregate with online segment-softmax (wave per node, 2 edges in flight)
__global__ void gat_agg_kernel(const int* __restrict__ rowptr, const int* __restrict__ csr_src,
                               const float* __restrict__ g, const float* __restrict__ a_s,
                               const float* __restrict__ a_d, const float* __restrict__ b2,
                               float* __restrict__ out, int N) {
    const int lane = threadIdx.x & 63;
    const int c = lane & 31, half = lane >> 5;
    const int wib = threadIdx.x >> 6;
    for (int i = blockIdx.x * 4 + wib; i < N; i += gridDim.x * 4) {
        const int b = rowptr[i], e = rowptr[i + 1];
        const float adi = a_d[i];
        float m = -__builtin_inff(), ssum = 0.0f, acc = 0.0f;
        for (int j = b + half; j < e; j += 2) {
            int s = csr_src[j];
            float ev = a_s[s] + adi;
            ev = ev > 0.0f ? ev : NEG_SLOPE * ev;
            float mn = fmaxf(m, ev);
            float scale = __expf(m - mn);
            float w = __expf(ev - mn);
            ssum = ssum * scale + w;
            acc  = acc  * scale + w * g[(long long)s * D_OUT + c];
            m = mn;
        }
        float mo = __shfl_xor(m, 32);
        float so = __shfl_xor(ssum, 32);
        float ao = __shfl_xor(acc, 32);
        float M = fmaxf(m, mo);
        float e0 = __expf(m - M), e1 = __expf(mo - M);
        float S = ssum * e0 + so * e1;
        float A = acc  * e0 + ao * e1;
        if (half == 0) {
            out[(long long)i * D_OUT + c] = A / (S + EPS_F) + b2[c];
        }
    }
}

extern "C" void kernel_launch(void* const* d_in, const int* in_sizes, int n_in,
                              void* d_out, int out_size, void* d_ws, size_t ws_size,
                              hipStream_t stream) {
    const float* x       = (const float*)d_in[0];
    const int*   ei      = (const int*)d_in[1];   // int32 or int64, detected on device
    const float* W1      = (const float*)d_in[2];
    const float* b1      = (const float*)d_in[3];
    const float* W2      = (const float*)d_in[4];
    const float* att_src = (const float*)d_in[5];
    const float* att_dst = (const float*)d_in[6];
    const float* b2      = (const float*)d_in[7];
    float* out = (float*)d_out;

    const long long N  = in_sizes[0] / D_IN;
    const long long E  = in_sizes[1] / 2;
    const long long E2 = E + N;
    const int NB = (int)((N + SCAN_CHUNK - 1) / SCAN_CHUNK);
    const int K2 = (int)((N + (1 << BKT2_SHIFT) - 1) >> BKT2_SHIFT);  // 25 for N=100K

    // workspace layout (256B aligned slices)
    char* ws = (char*)d_ws;
    size_t off = 0;
    auto alloc = [&](size_t bytes) -> void* {
        off = (off + 255) & ~(size_t)255;
        void* p = ws + off;
        off += bytes;
        return p;
    };
    int*   flag     = (int*)  alloc(16);
    // cnt, chunkcur, tailcur contiguous -> single memset
    int*   cnt      = (int*)  alloc(((size_t)N + 2 * KBUKMAX) * 4);
    int*   chunkcur = cnt + N;
    int*   tailcur  = chunkcur + KBUKMAX;
    int*   rowptr   = (int*)  alloc((size_t)(N + 1) * 4);
    int*   csr_src  = (int*)  alloc((size_t)E2 * 4);
    float* dis      = (float*)alloc((size_t)N * 4);
    float* hws      = (float*)alloc((size_t)N * D_HID * 4);
    float* h1       = (float*)alloc((size_t)N * D_HID * 4);
    float* gbuf     = (float*)alloc((size_t)N * D_OUT * 4);
    float* as       = (float*)alloc((size_t)N * 4);
    float* ad       = (float*)alloc((size_t)N * 4);
    int*   blocksum = (int*)  alloc((size_t)NB * 4);
    unsigned* binsg = (unsigned*)alloc((size_t)K2 * BKCAP * 4);
    unsigned* tails = (unsigned*)alloc((size_t)K2 * TCAP * 4);
    (void)ws_size; (void)n_in; (void)out_size;

    detect_kernel<<<1, 64, 0, stream>>>(ei, E, flag);
    hipMemsetAsync(cnt, 0, ((size_t)N + 2 * KBUKMAX) * 4, stream);
    bin_a_kernel<<<256, 256, 0, stream>>>(ei, flag, E, E2, cnt, chunkcur, tailcur, binsg, tails, K2);
    scan_a_kernel<<<NB, 256, 0, stream>>>(cnt, rowptr, dis, blocksum, (int)N);
    scan_b_kernel<<<1, 1024, 0, stream>>>(blocksum, rowptr, NB, (int)N, (int)E2);
    scan_c_kernel<<<(int)((N + 255) / 256), 256, 0, stream>>>(rowptr, blocksum, (int)N);
    fill3_kernel<<<K2, 1024, 0, stream>>>(binsg, tails, chunkcur, tailcur, rowptr, csr_src, (int)N, K2);
    gemm1_kernel<<<1024, 256, 0, stream>>>(x, W1, dis, hws, (int)N);
    int agg_blocks = (int)((N + 3) / 4);
    gcn_agg_kernel<<<agg_blocks, 256, 0, stream>>>(rowptr, csr_src, hws, dis, b1, h1, (int)N);
    gemm2_kernel<<<1024, 256, 0, stream>>>(h1, W2, att_src, att_dst, gbuf, as, ad, (int)N);
    gat_agg_kernel<<<agg_blocks, 256, 0, stream>>>(rowptr, csr_src, gbuf, as, ad, b2, out, (int)N);
}

// Round 5
// 367.628 us; speedup vs baseline: 3.3181x; 3.3181x over previous
//
#include <hip/hip_runtime.h>
#include <cstdint>
#include <cstddef>

#define D_IN   128
#define D_HID  32
#define D_OUT  32
#define NEG_SLOPE 0.2f
#define EPS_F  1e-16f
#define SCAN_CHUNK 1024   // elements per block in scan phase A (256 thr x 4)

#define BKT_SHIFT 12      // 4096 nodes per bucket
#define KBUKMAX 32        // supports N <= 131072
#define NBLK_BIN 1024     // blocks for hist/scatter

// ---------------------------------------------------------------------------
// edge_index may arrive as int32 or int64. Detect on device: values < 2^17,
// so int64 => every odd int32 word (high half, LE) of the first 64 pairs is 0.
// ---------------------------------------------------------------------------
__global__ void detect_kernel(const int* __restrict__ ei, long long E, int* __restrict__ flag) {
    const int t = threadIdx.x;                     // 64 threads
    long long n = E < 64 ? E : 64;
    int bad = (t < n && ei[2 * t + 1] != 0) ? 1 : 0;
    unsigned long long mask = __ballot(bad);
    if (t == 0) *flag = (mask == 0ULL) ? 1 : 0;
}

__device__ __forceinline__ int edge_val(const int* __restrict__ ei, long long idx, int is64) {
    return is64 ? ei[idx * 2] : ei[idx];
}

// ---------------------------------------------------------------------------
// Multi-split pass 1: per-block bucket histogram (LDS), dense write-out.
// No global atomics. hist layout: [bucket][block] (bucket-major).
// ---------------------------------------------------------------------------
__global__ __launch_bounds__(256) void hist_kernel(
        const int* __restrict__ ei, const int* __restrict__ flag,
        long long E, long long E2, int* __restrict__ hist, int K2, int EPB) {
    __shared__ int hcnt[KBUKMAX];
    const int is64 = *flag;
    const int t = threadIdx.x;
    if (t < K2) hcnt[t] = 0;
    __syncthreads();
    const long long lo = (long long)blockIdx.x * EPB;
    const long long hi = min(E2, lo + EPB);
    for (long long e = lo + t; e < hi; e += 256) {
        int d = (e < E) ? edge_val(ei, E + e, is64) : (int)(e - E);
        atomicAdd(&hcnt[d >> BKT_SHIFT], 1);
    }
    __syncthreads();
    if (t < K2) hist[t * gridDim.x + blockIdx.x] = hcnt[t];
}

// Single-block in-place exclusive scan of a[L] (generic, L up to ~64K fast)
__global__ __launch_bounds__(1024) void scan_flat_kernel(int* __restrict__ a, int L) {
    __shared__ int wsum[16];
    __shared__ int carry_s;
    const int t = threadIdx.x;
    const int lane = t & 63, wid = t >> 6;
    if (t == 0) carry_s = 0;
    __syncthreads();
    for (int start = 0; start < L; start += 1024) {
        int idx = start + t;
        int v = (idx < L) ? a[idx] : 0;
        int incl = v;
        #pragma unroll
        for (int d = 1; d < 64; d <<= 1) {
            int u = __shfl_up(incl, d);
            if (lane >= d) incl += u;
        }
        if (lane == 63) wsum[wid] = incl;
        __syncthreads();
        int woff = 0;
        for (int w = 0; w < wid; ++w) woff += wsum[w];
        int carry = carry_s;
        __syncthreads();
        if (idx < L) a[idx] = carry + woff + incl - v;
        if (t == 1023) carry_s = carry + woff + incl;
        __syncthreads();
    }
}

// ---------------------------------------------------------------------------
// Multi-split pass 2: scatter packed (src | dlow<<17) into bins. Each
// (bucket,block) run is block-private & contiguous -> one XCD per line,
// lines filled within the block's lifetime -> dense writeback. No global
// atomics (offsets come from the scanned histogram).
// ---------------------------------------------------------------------------
__global__ __launch_bounds__(256) void scatter_kernel(
        const int* __restrict__ ei, const int* __restrict__ flag,
        long long E, long long E2, const int* __restrict__ off,
        unsigned* __restrict__ bins, int K2, int EPB) {
    __shared__ int cur[KBUKMAX];
    const int is64 = *flag;
    const int t = threadIdx.x;
    if (t < K2) cur[t] = off[t * gridDim.x + blockIdx.x];
    __syncthreads();
    const long long lo = (long long)blockIdx.x * EPB;
    const long long hi = min(E2, lo + EPB);
    for (long long e = lo + t; e < hi; e += 256) {
        int s, d;
        if (e < E) { s = edge_val(ei, e, is64); d = edge_val(ei, E + e, is64); }
        else       { s = d = (int)(e - E); }
        int b = d >> BKT_SHIFT;
        int pos = atomicAdd(&cur[b], 1);
        bins[pos] = (unsigned)s | ((unsigned)(d & 4095) << 17);
    }
}

// ---------------------------------------------------------------------------
// Per-bucket node-degree count: one block per bucket, LDS counters, dense
// cnt write. Replaces 1.7M global atomics.
// ---------------------------------------------------------------------------
__global__ __launch_bounds__(1024) void cnt_b_kernel(
        const unsigned* __restrict__ bins, const int* __restrict__ off,
        int* __restrict__ cnt, int N, int K2, long long E2) {
    __shared__ int lc[1 << BKT_SHIFT];             // 16 KB
    const int b = blockIdx.x;
    const int t = threadIdx.x;
    for (int i = t; i < (1 << BKT_SHIFT); i += 1024) lc[i] = 0;
    __syncthreads();
    const int base = off[b * NBLK_BIN];
    const int end  = (b == K2 - 1) ? (int)E2 : off[(b + 1) * NBLK_BIN];
    for (int i = base + t; i < end; i += 1024)
        atomicAdd(&lc[bins[i] >> 17], 1);
    __syncthreads();
    const int nbase = b << BKT_SHIFT;
    const int nn = min(1 << BKT_SHIFT, N - nbase);
    for (int i = t; i < nn; i += 1024) cnt[nbase + i] = lc[i];
}

// ---------------- hierarchical scan: cnt[N] -> rowptr/dis -----------------
__global__ void scan_a_kernel(const int* __restrict__ cnt, int* __restrict__ rowptr,
                              float* __restrict__ dis, int* __restrict__ blocksum, int N) {
    __shared__ int wsum[4];                        // 256 threads = 4 waves
    const int t = threadIdx.x;
    const int base = blockIdx.x * SCAN_CHUNK;
    const int i0 = base + t * 4;
    int v[4];
    int s = 0;
    if (i0 + 4 <= N) {
        int4 c4 = *(const int4*)(cnt + i0);
        v[0] = c4.x; v[1] = c4.y; v[2] = c4.z; v[3] = c4.w;
        #pragma unroll
        for (int k = 0; k < 4; ++k) {
            s += v[k];
            dis[i0 + k] = rsqrtf((float)v[k]);     // deg >= 1 (self-loop)
        }
    } else {
        #pragma unroll
        for (int k = 0; k < 4; ++k) {
            int idx = i0 + k;
            int c = (idx < N) ? cnt[idx] : 0;
            v[k] = c; s += c;
            if (idx < N) dis[idx] = rsqrtf((float)c);
        }
    }
    const int lane = t & 63, wid = t >> 6;
    int incl = s;
    #pragma unroll
    for (int d = 1; d < 64; d <<= 1) {
        int u = __shfl_up(incl, d);
        if (lane >= d) incl += u;
    }
    if (lane == 63) wsum[wid] = incl;
    __syncthreads();
    int woff = 0;
    for (int w = 0; w < wid; ++w) woff += wsum[w];
    int excl = woff + incl - s;
    #pragma unroll
    for (int k = 0; k < 4; ++k) {
        int idx = i0 + k;
        if (idx < N) rowptr[idx] = excl;
        excl += v[k];
    }
    if (t == 255) blocksum[blockIdx.x] = woff + incl;
}

__global__ void scan_b_kernel(int* __restrict__ blocksum, int* __restrict__ rowptr,
                              int NB, int N, int total) {
    __shared__ int wsum[16];
    __shared__ int carry_s;
    const int t = threadIdx.x;                     // 1024
    const int lane = t & 63, wid = t >> 6;
    if (t == 0) carry_s = 0;
    __syncthreads();
    for (int start = 0; start < NB; start += 1024) {
        int idx = start + t;
        int v = (idx < NB) ? blocksum[idx] : 0;
        int incl = v;
        #pragma unroll
        for (int d = 1; d < 64; d <<= 1) {
            int u = __shfl_up(incl, d);
            if (lane >= d) incl += u;
        }
        if (lane == 63) wsum[wid] = incl;
        __syncthreads();
        int woff = 0;
        for (int w = 0; w < wid; ++w) woff += wsum[w];
        int carry = carry_s;
        __syncthreads();
        if (idx < NB) blocksum[idx] = carry + woff + incl - v;
        if (t == 1023) carry_s = carry + woff + incl;
        __syncthreads();
    }
    if (t == 0) rowptr[N] = total;
}

__global__ void scan_c_kernel(int* __restrict__ rowptr, const int* __restrict__ blocksum, int N) {
    int idx = blockIdx.x * blockDim.x + threadIdx.x;
    if (idx < N) rowptr[idx] += blocksum[idx / SCAN_CHUNK];
}

// ---------------------------------------------------------------------------
// Per-bucket CSR fill: LDS cursors, single CU owns the ~280 KB window ->
// lines go fully dirty inside one L2 -> dense writeback.
// ---------------------------------------------------------------------------
__global__ __launch_bounds__(1024) void fill_b_kernel(
        const unsigned* __restrict__ bins, const int* __restrict__ off,
        const int* __restrict__ rowptr, int* __restrict__ csr_src,
        int N, int K2, long long E2) {
    __shared__ int lcur[1 << BKT_SHIFT];           // 16 KB
    const int b = blockIdx.x;
    const int t = threadIdx.x;
    const int nbase = b << BKT_SHIFT;
    const int nn = min(1 << BKT_SHIFT, N - nbase);
    for (int i = t; i < nn; i += 1024) lcur[i] = rowptr[nbase + i];
    __syncthreads();
    const int base = off[b * NBLK_BIN];
    const int end  = (b == K2 - 1) ? (int)E2 : off[(b + 1) * NBLK_BIN];
    for (int i = base + t; i < end; i += 1024) {
        unsigned u = bins[i];
        int pos = atomicAdd(&lcur[u >> 17], 1);
        csr_src[pos] = (int)(u & 0x1FFFFu);
    }
}

// hws[i][:] = dis[i] * (x[i] @ W1)      (pre-scaled so GCN gather needs no dis[src])
__global__ void gemm1_kernel(const float* __restrict__ x, const float* __restrict__ W1,
                             const float* __restrict__ dis, float* __restrict__ hws, int N) {
    __shared__ float sW[D_IN * D_HID];      // 16 KB
    __shared__ float sx[8][D_IN];           // 4 KB
    const int t = threadIdx.x;              // 256
    const int c = t & 31, r = t >> 5;
    for (int i = t; i < D_IN * D_HID; i += 256) sW[i] = W1[i];
    for (long long base = (long long)blockIdx.x * 8; base < N; base += (long long)gridDim.x * 8) {
        __syncthreads();
        if (base + 8 <= N) {
            const float4* xp = (const float4*)(x + base * D_IN);
            float4 v = xp[t];
            sx[t >> 5][(t & 31) * 4 + 0] = v.x;
            sx[t >> 5][(t & 31) * 4 + 1] = v.y;
            sx[t >> 5][(t & 31) * 4 + 2] = v.z;
            sx[t >> 5][(t & 31) * 4 + 3] = v.w;
        } else {
            long long nrem = (N - base) * D_IN;
            for (int i = t; i < nrem; i += 256) sx[i >> 7][i & 127] = x[base * D_IN + i];
        }
        __syncthreads();
        long long row = base + r;
        if (row < N) {
            float acc = 0.0f;
            #pragma unroll 16
            for (int k = 0; k < D_IN; ++k) acc = fmaf(sx[r][k], sW[k * D_HID + c], acc);
            hws[row * D_HID + c] = acc * dis[row];
        }
    }
}

// GCN aggregate + bias + ReLU
__global__ void gcn_agg_kernel(const int* __restrict__ rowptr, const int* __restrict__ csr_src,
                               const float* __restrict__ hws, const float* __restrict__ dis,
                               const float* __restrict__ b1, float* __restrict__ h1, int N) {
    const int lane = threadIdx.x & 63;
    const int c = lane & 31, half = lane >> 5;
    const int wib = threadIdx.x >> 6;       // 4 waves / block
    for (int i = blockIdx.x * 4 + wib; i < N; i += gridDim.x * 4) {
        const int b = rowptr[i], e = rowptr[i + 1];
        float acc = 0.0f;
        for (int j = b + half; j < e; j += 2) {
            int s = csr_src[j];
            acc += hws[(long long)s * D_HID + c];
        }
        acc += __shfl_xor(acc, 32);
        if (half == 0) {
            float v = dis[i] * acc + b1[c];
            h1[(long long)i * D_HID + c] = v > 0.0f ? v : 0.0f;
        }
    }
}

// g = h1 @ W2 ; a_s = g @ att_src ; a_d = g @ att_dst
__global__ void gemm2_kernel(const float* __restrict__ h1, const float* __restrict__ W2,
                             const float* __restrict__ att_s, const float* __restrict__ att_d,
                             float* __restrict__ g, float* __restrict__ a_s, float* __restrict__ a_d,
                             int N) {
    __shared__ float sW[D_HID * D_OUT];     // 4 KB
    __shared__ float sas[D_OUT], sad[D_OUT];
    __shared__ float sh[8][D_HID];          // 1 KB
    const int t = threadIdx.x;              // 256
    const int c = t & 31, r = t >> 5;
    for (int i = t; i < D_HID * D_OUT; i += 256) sW[i] = W2[i];
    if (t < D_OUT) { sas[t] = att_s[t]; sad[t] = att_d[t]; }
    for (long long base = (long long)blockIdx.x * 8; base < N; base += (long long)gridDim.x * 8) {
        __syncthreads();
        if (base * D_HID + t < (long long)N * D_HID) sh[r][c] = h1[base * D_HID + t];
        __syncthreads();
        long long row = base + r;
        if (row < N) {
            float gv = 0.0f;
            #pragma unroll
            for (int k = 0; k < D_HID; ++k) gv = fmaf(sh[r][k], sW[k * D_OUT + c], gv);
            g[row * D_OUT + c] = gv;
            float ps = gv * sas[c];
            float pd = gv * sad[c];
            #pragma unroll
            for (int d = 16; d >= 1; d >>= 1) {
                ps += __shfl_xor(ps, d);
                pd += __shfl_xor(pd, d);
            }
            if (c == 0) { a_s[row] = ps; a_d[row] = pd; }
        }
    }
}

// GAT aggregate with online segment-softmax (wave per node, 2 edges in flight)
__global__ void gat_agg_kernel(const int* __restrict__ rowptr, const int* __restrict__ csr_src,
                               const float* __restrict__ g, const float* __restrict__ a_s,
                               const float* __restrict__ a_d, const float* __restrict__ b2,
                               float* __restrict__ out, int N) {
    const int lane = threadIdx.x & 63;
    const int c = lane & 31, half = lane >> 5;
    const int wib = threadIdx.x >> 6;
    for (int i = blockIdx.x * 4 + wib; i < N; i += gridDim.x * 4) {
        const int b = rowptr[i], e = rowptr[i + 1];
        const float adi = a_d[i];
        float m = -__builtin_inff(), ssum = 0.0f, acc = 0.0f;
        for (int j = b + half; j < e; j += 2) {
            int s = csr_src[j];
            float ev = a_s[s] + adi;
            ev = ev > 0.0f ? ev : NEG_SLOPE * ev;
            float mn = fmaxf(m, ev);
            float scale = __expf(m - mn);
            float w = __expf(ev - mn);
            ssum = ssum * scale + w;
            acc  = acc  * scale + w * g[(long long)s * D_OUT + c];
            m = mn;
        }
        float mo = __shfl_xor(m, 32);
        float so = __shfl_xor(ssum, 32);
        float ao = __shfl_xor(acc, 32);
        float M = fmaxf(m, mo);
        float e0 = __expf(m - M), e1 = __expf(mo - M);
        float S = ssum * e0 + so * e1;
        float A = acc  * e0 + ao * e1;
        if (half == 0) {
            out[(long long)i * D_OUT + c] = A / (S + EPS_F) + b2[c];
        }
    }
}

extern "C" void kernel_launch(void* const* d_in, const int* in_sizes, int n_in,
                              void* d_out, int out_size, void* d_ws, size_t ws_size,
                              hipStream_t stream) {
    const float* x       = (const float*)d_in[0];
    const int*   ei      = (const int*)d_in[1];   // int32 or int64, detected on device
    const float* W1      = (const float*)d_in[2];
    const float* b1      = (const float*)d_in[3];
    const float* W2      = (const float*)d_in[4];
    const float* att_src = (const float*)d_in[5];
    const float* att_dst = (const float*)d_in[6];
    const float* b2      = (const float*)d_in[7];
    float* out = (float*)d_out;

    const long long N  = in_sizes[0] / D_IN;
    const long long E  = in_sizes[1] / 2;
    const long long E2 = E + N;
    const int NB = (int)((N + SCAN_CHUNK - 1) / SCAN_CHUNK);
    const int K2 = (int)((N + (1 << BKT_SHIFT) - 1) >> BKT_SHIFT);   // 25 for N=100K
    const int EPB = (int)((E2 + NBLK_BIN - 1) / NBLK_BIN);

    // workspace layout (256B aligned slices)
    char* ws = (char*)d_ws;
    size_t off0 = 0;
    auto alloc = [&](size_t bytes) -> void* {
        off0 = (off0 + 255) & ~(size_t)255;
        void* p = ws + off0;
        off0 += bytes;
        return p;
    };
    int*   flag     = (int*)  alloc(16);
    int*   hist     = (int*)  alloc((size_t)KBUKMAX * NBLK_BIN * 4);
    unsigned* bins  = (unsigned*)alloc((size_t)E2 * 4);
    int*   cnt      = (int*)  alloc((size_t)N * 4);
    int*   rowptr   = (int*)  alloc((size_t)(N + 1) * 4);
    int*   csr_src  = (int*)  alloc((size_t)E2 * 4);
    float* dis      = (float*)alloc((size_t)N * 4);
    float* hws      = (float*)alloc((size_t)N * D_HID * 4);
    float* h1       = (float*)alloc((size_t)N * D_HID * 4);
    float* gbuf     = (float*)alloc((size_t)N * D_OUT * 4);
    float* as       = (float*)alloc((size_t)N * 4);
    float* ad       = (float*)alloc((size_t)N * 4);
    int*   blocksum = (int*)  alloc((size_t)NB * 4);
    (void)ws_size; (void)n_in; (void)out_size;

    detect_kernel<<<1, 64, 0, stream>>>(ei, E, flag);
    hist_kernel<<<NBLK_BIN, 256, 0, stream>>>(ei, flag, E, E2, hist, K2, EPB);
    scan_flat_kernel<<<1, 1024, 0, stream>>>(hist, K2 * NBLK_BIN);
    scatter_kernel<<<NBLK_BIN, 256, 0, stream>>>(ei, flag, E, E2, hist, bins, K2, EPB);
    cnt_b_kernel<<<K2, 1024, 0, stream>>>(bins, hist, cnt, (int)N, K2, E2);
    scan_a_kernel<<<NB, 256, 0, stream>>>(cnt, rowptr, dis, blocksum, (int)N);
    scan_b_kernel<<<1, 1024, 0, stream>>>(blocksum, rowptr, NB, (int)N, (int)E2);
    scan_c_kernel<<<(int)((N + 255) / 256), 256, 0, stream>>>(rowptr, blocksum, (int)N);
    fill_b_kernel<<<K2, 1024, 0, stream>>>(bins, hist, rowptr, csr_src, (int)N, K2, E2);
    gemm1_kernel<<<1024, 256, 0, stream>>>(x, W1, dis, hws, (int)N);
    int agg_blocks = (int)((N + 3) / 4);
    gcn_agg_kernel<<<agg_blocks, 256, 0, stream>>>(rowptr, csr_src, hws, dis, b1, h1, (int)N);
    gemm2_kernel<<<1024, 256, 0, stream>>>(h1, W2, att_src, att_dst, gbuf, as, ad, (int)N);
    gat_agg_kernel<<<agg_blocks, 256, 0, stream>>>(rowptr, csr_src, gbuf, as, ad, b2, out, (int)N);
}

// Round 6
// 273.736 us; speedup vs baseline: 4.4563x; 1.3430x over previous
//
#include <hip/hip_runtime.h>
#include <cstdint>
#include <cstddef>

#define D_IN   128
#define D_HID  32
#define D_OUT  32
#define NEG_SLOPE 0.2f
#define EPS_F  1e-16f
#define SCAN_CHUNK 1024   // elements per block in scan phase A (256 thr x 4)

#define BKT_SHIFT 12      // 4096 nodes per bucket
#define KBUKMAX 32        // supports N <= 131072
#define NBLK_BIN 1024     // blocks for hist/scatter

// ---------------------------------------------------------------------------
// edge_index may arrive as int32 or int64. Detect on device: values < 2^17,
// so int64 => every odd int32 word (high half, LE) of the first 64 pairs is 0.
// ---------------------------------------------------------------------------
__global__ void detect_kernel(const int* __restrict__ ei, long long E, int* __restrict__ flag) {
    const int t = threadIdx.x;                     // 64 threads
    long long n = E < 64 ? E : 64;
    int bad = (t < n && ei[2 * t + 1] != 0) ? 1 : 0;
    unsigned long long mask = __ballot(bad);
    if (t == 0) *flag = (mask == 0ULL) ? 1 : 0;
}

__device__ __forceinline__ int edge_val(const int* __restrict__ ei, long long idx, int is64) {
    return is64 ? ei[idx * 2] : ei[idx];
}

// ---------------------------------------------------------------------------
// Multi-split pass 1: per-block bucket histogram (LDS), dense write-out.
// No global atomics. hist layout: [bucket][block] (bucket-major).
// ---------------------------------------------------------------------------
__global__ __launch_bounds__(256) void hist_kernel(
        const int* __restrict__ ei, const int* __restrict__ flag,
        long long E, long long E2, int* __restrict__ hist, int K2, int EPB) {
    __shared__ int hcnt[KBUKMAX];
    const int is64 = *flag;
    const int t = threadIdx.x;
    if (t < K2) hcnt[t] = 0;
    __syncthreads();
    const long long lo = (long long)blockIdx.x * EPB;
    const long long hi = min(E2, lo + EPB);
    for (long long e = lo + t; e < hi; e += 256) {
        int d = (e < E) ? edge_val(ei, E + e, is64) : (int)(e - E);
        atomicAdd(&hcnt[d >> BKT_SHIFT], 1);
    }
    __syncthreads();
    if (t < K2) hist[t * gridDim.x + blockIdx.x] = hcnt[t];
}

// Single-block in-place exclusive scan of a[L]
__global__ __launch_bounds__(1024) void scan_flat_kernel(int* __restrict__ a, int L) {
    __shared__ int wsum[16];
    __shared__ int carry_s;
    const int t = threadIdx.x;
    const int lane = t & 63, wid = t >> 6;
    if (t == 0) carry_s = 0;
    __syncthreads();
    for (int start = 0; start < L; start += 1024) {
        int idx = start + t;
        int v = (idx < L) ? a[idx] : 0;
        int incl = v;
        #pragma unroll
        for (int d = 1; d < 64; d <<= 1) {
            int u = __shfl_up(incl, d);
            if (lane >= d) incl += u;
        }
        if (lane == 63) wsum[wid] = incl;
        __syncthreads();
        int woff = 0;
        for (int w = 0; w < wid; ++w) woff += wsum[w];
        int carry = carry_s;
        __syncthreads();
        if (idx < L) a[idx] = carry + woff + incl - v;
        if (t == 1023) carry_s = carry + woff + incl;
        __syncthreads();
    }
}

// ---------------------------------------------------------------------------
// Multi-split pass 2: scatter packed (src | dlow<<17) into bins. Each
// (bucket,block) run is block-private & contiguous -> dense writeback.
// ---------------------------------------------------------------------------
__global__ __launch_bounds__(256) void scatter_kernel(
        const int* __restrict__ ei, const int* __restrict__ flag,
        long long E, long long E2, const int* __restrict__ off,
        unsigned* __restrict__ bins, int K2, int EPB) {
    __shared__ int cur[KBUKMAX];
    const int is64 = *flag;
    const int t = threadIdx.x;
    if (t < K2) cur[t] = off[t * gridDim.x + blockIdx.x];
    __syncthreads();
    const long long lo = (long long)blockIdx.x * EPB;
    const long long hi = min(E2, lo + EPB);
    for (long long e = lo + t; e < hi; e += 256) {
        int s, d;
        if (e < E) { s = edge_val(ei, e, is64); d = edge_val(ei, E + e, is64); }
        else       { s = d = (int)(e - E); }
        int b = d >> BKT_SHIFT;
        int pos = atomicAdd(&cur[b], 1);
        bins[pos] = (unsigned)s | ((unsigned)(d & 4095) << 17);
    }
}

// Per-bucket node-degree count: one block per bucket, LDS counters.
__global__ __launch_bounds__(1024) void cnt_b_kernel(
        const unsigned* __restrict__ bins, const int* __restrict__ off,
        int* __restrict__ cnt, int N, int K2, long long E2) {
    __shared__ int lc[1 << BKT_SHIFT];             // 16 KB
    const int b = blockIdx.x;
    const int t = threadIdx.x;
    for (int i = t; i < (1 << BKT_SHIFT); i += 1024) lc[i] = 0;
    __syncthreads();
    const int base = off[b * NBLK_BIN];
    const int end  = (b == K2 - 1) ? (int)E2 : off[(b + 1) * NBLK_BIN];
    for (int i = base + t; i < end; i += 1024)
        atomicAdd(&lc[bins[i] >> 17], 1);
    __syncthreads();
    const int nbase = b << BKT_SHIFT;
    const int nn = min(1 << BKT_SHIFT, N - nbase);
    for (int i = t; i < nn; i += 1024) cnt[nbase + i] = lc[i];
}

// ---------------- hierarchical scan: cnt[N] -> rowptr/dis -----------------
__global__ void scan_a_kernel(const int* __restrict__ cnt, int* __restrict__ rowptr,
                              float* __restrict__ dis, int* __restrict__ blocksum, int N) {
    __shared__ int wsum[4];                        // 256 threads = 4 waves
    const int t = threadIdx.x;
    const int base = blockIdx.x * SCAN_CHUNK;
    const int i0 = base + t * 4;
    int v[4];
    int s = 0;
    if (i0 + 4 <= N) {
        int4 c4 = *(const int4*)(cnt + i0);
        v[0] = c4.x; v[1] = c4.y; v[2] = c4.z; v[3] = c4.w;
        #pragma unroll
        for (int k = 0; k < 4; ++k) {
            s += v[k];
            dis[i0 + k] = rsqrtf((float)v[k]);     // deg >= 1 (self-loop)
        }
    } else {
        #pragma unroll
        for (int k = 0; k < 4; ++k) {
            int idx = i0 + k;
            int c = (idx < N) ? cnt[idx] : 0;
            v[k] = c; s += c;
            if (idx < N) dis[idx] = rsqrtf((float)c);
        }
    }
    const int lane = t & 63, wid = t >> 6;
    int incl = s;
    #pragma unroll
    for (int d = 1; d < 64; d <<= 1) {
        int u = __shfl_up(incl, d);
        if (lane >= d) incl += u;
    }
    if (lane == 63) wsum[wid] = incl;
    __syncthreads();
    int woff = 0;
    for (int w = 0; w < wid; ++w) woff += wsum[w];
    int excl = woff + incl - s;
    #pragma unroll
    for (int k = 0; k < 4; ++k) {
        int idx = i0 + k;
        if (idx < N) rowptr[idx] = excl;
        excl += v[k];
    }
    if (t == 255) blocksum[blockIdx.x] = woff + incl;
}

__global__ void scan_b_kernel(int* __restrict__ blocksum, int* __restrict__ rowptr,
                              int NB, int N, int total) {
    __shared__ int wsum[16];
    __shared__ int carry_s;
    const int t = threadIdx.x;                     // 1024
    const int lane = t & 63, wid = t >> 6;
    if (t == 0) carry_s = 0;
    __syncthreads();
    for (int start = 0; start < NB; start += 1024) {
        int idx = start + t;
        int v = (idx < NB) ? blocksum[idx] : 0;
        int incl = v;
        #pragma unroll
        for (int d = 1; d < 64; d <<= 1) {
            int u = __shfl_up(incl, d);
            if (lane >= d) incl += u;
        }
        if (lane == 63) wsum[wid] = incl;
        __syncthreads();
        int woff = 0;
        for (int w = 0; w < wid; ++w) woff += wsum[w];
        int carry = carry_s;
        __syncthreads();
        if (idx < NB) blocksum[idx] = carry + woff + incl - v;
        if (t == 1023) carry_s = carry + woff + incl;
        __syncthreads();
    }
    if (t == 0) rowptr[N] = total;
}

__global__ void scan_c_kernel(int* __restrict__ rowptr, const int* __restrict__ blocksum, int N) {
    int idx = blockIdx.x * blockDim.x + threadIdx.x;
    if (idx < N) rowptr[idx] += blocksum[idx / SCAN_CHUNK];
}

// Per-bucket CSR fill: LDS cursors, single CU owns the window.
__global__ __launch_bounds__(1024) void fill_b_kernel(
        const unsigned* __restrict__ bins, const int* __restrict__ off,
        const int* __restrict__ rowptr, int* __restrict__ csr_src,
        int N, int K2, long long E2) {
    __shared__ int lcur[1 << BKT_SHIFT];           // 16 KB
    const int b = blockIdx.x;
    const int t = threadIdx.x;
    const int nbase = b << BKT_SHIFT;
    const int nn = min(1 << BKT_SHIFT, N - nbase);
    for (int i = t; i < nn; i += 1024) lcur[i] = rowptr[nbase + i];
    __syncthreads();
    const int base = off[b * NBLK_BIN];
    const int end  = (b == K2 - 1) ? (int)E2 : off[(b + 1) * NBLK_BIN];
    for (int i = base + t; i < end; i += 1024) {
        unsigned u = bins[i];
        int pos = atomicAdd(&lcur[u >> 17], 1);
        csr_src[pos] = (int)(u & 0x1FFFFu);
    }
}

// hws[i][:] = dis[i] * (x[i] @ W1)      (pre-scaled so GCN gather needs no dis[src])
__global__ void gemm1_kernel(const float* __restrict__ x, const float* __restrict__ W1,
                             const float* __restrict__ dis, float* __restrict__ hws, int N) {
    __shared__ float sW[D_IN * D_HID];      // 16 KB
    __shared__ float sx[8][D_IN];           // 4 KB
    const int t = threadIdx.x;              // 256
    const int c = t & 31, r = t >> 5;
    for (int i = t; i < D_IN * D_HID; i += 256) sW[i] = W1[i];
    for (long long base = (long long)blockIdx.x * 8; base < N; base += (long long)gridDim.x * 8) {
        __syncthreads();
        if (base + 8 <= N) {
            const float4* xp = (const float4*)(x + base * D_IN);
            float4 v = xp[t];
            sx[t >> 5][(t & 31) * 4 + 0] = v.x;
            sx[t >> 5][(t & 31) * 4 + 1] = v.y;
            sx[t >> 5][(t & 31) * 4 + 2] = v.z;
            sx[t >> 5][(t & 31) * 4 + 3] = v.w;
        } else {
            long long nrem = (N - base) * D_IN;
            for (int i = t; i < nrem; i += 256) sx[i >> 7][i & 127] = x[base * D_IN + i];
        }
        __syncthreads();
        long long row = base + r;
        if (row < N) {
            float acc = 0.0f;
            #pragma unroll 16
            for (int k = 0; k < D_IN; ++k) acc = fmaf(sx[r][k], sW[k * D_HID + c], acc);
            hws[row * D_HID + c] = acc * dis[row];
        }
    }
}

// ---------------------------------------------------------------------------
// GCN aggregate + bias + ReLU. 8 edges in flight per wave: 8 groups x 8
// lanes, each lane holds float4 of the 32-float row (8x16B = 128B/edge).
// ---------------------------------------------------------------------------
__global__ void gcn_agg_kernel(const int* __restrict__ rowptr, const int* __restrict__ csr_src,
                               const float* __restrict__ hws, const float* __restrict__ dis,
                               const float* __restrict__ b1, float* __restrict__ h1, int N) {
    const int lane = threadIdx.x & 63;
    const int u = lane & 7, grp = lane >> 3;       // 8 groups x 8 lanes
    const int wib = threadIdx.x >> 6;              // 4 waves / block
    const float4* hws4 = (const float4*)hws;
    float4* h14 = (float4*)h1;
    const float4 b14 = ((const float4*)b1)[u];
    for (int i = blockIdx.x * 4 + wib; i < N; i += gridDim.x * 4) {
        const int b = rowptr[i], e = rowptr[i + 1];
        float ax = 0.f, ay = 0.f, az = 0.f, aw = 0.f;
        for (int j = b + grp; j < e; j += 8) {
            int s = csr_src[j];
            float4 hv = hws4[s * 8 + u];
            ax += hv.x; ay += hv.y; az += hv.z; aw += hv.w;
        }
        #pragma unroll
        for (int d = 8; d <= 32; d <<= 1) {
            ax += __shfl_xor(ax, d); ay += __shfl_xor(ay, d);
            az += __shfl_xor(az, d); aw += __shfl_xor(aw, d);
        }
        if (grp == 0) {
            float dd = dis[i];
            float4 o;
            o.x = fmaf(dd, ax, b14.x); o.y = fmaf(dd, ay, b14.y);
            o.z = fmaf(dd, az, b14.z); o.w = fmaf(dd, aw, b14.w);
            o.x = o.x > 0.f ? o.x : 0.f; o.y = o.y > 0.f ? o.y : 0.f;
            o.z = o.z > 0.f ? o.z : 0.f; o.w = o.w > 0.f ? o.w : 0.f;
            h14[(long long)i * 8 + u] = o;
        }
    }
}

// g = h1 @ W2 ; a_s = g @ att_src ; a_d = g @ att_dst
__global__ void gemm2_kernel(const float* __restrict__ h1, const float* __restrict__ W2,
                             const float* __restrict__ att_s, const float* __restrict__ att_d,
                             float* __restrict__ g, float* __restrict__ a_s, float* __restrict__ a_d,
                             int N) {
    __shared__ float sW[D_HID * D_OUT];     // 4 KB
    __shared__ float sas[D_OUT], sad[D_OUT];
    __shared__ float sh[8][D_HID];          // 1 KB
    const int t = threadIdx.x;              // 256
    const int c = t & 31, r = t >> 5;
    for (int i = t; i < D_HID * D_OUT; i += 256) sW[i] = W2[i];
    if (t < D_OUT) { sas[t] = att_s[t]; sad[t] = att_d[t]; }
    for (long long base = (long long)blockIdx.x * 8; base < N; base += (long long)gridDim.x * 8) {
        __syncthreads();
        if (base * D_HID + t < (long long)N * D_HID) sh[r][c] = h1[base * D_HID + t];
        __syncthreads();
        long long row = base + r;
        if (row < N) {
            float gv = 0.0f;
            #pragma unroll
            for (int k = 0; k < D_HID; ++k) gv = fmaf(sh[r][k], sW[k * D_OUT + c], gv);
            g[row * D_OUT + c] = gv;
            float ps = gv * sas[c];
            float pd = gv * sad[c];
            #pragma unroll
            for (int d = 16; d >= 1; d >>= 1) {
                ps += __shfl_xor(ps, d);
                pd += __shfl_xor(pd, d);
            }
            if (c == 0) { a_s[row] = ps; a_d[row] = pd; }
        }
    }
}

// ---------------------------------------------------------------------------
// GAT aggregate, online segment-softmax, 8 edges in flight per wave.
// Finite sentinel -1e30 (not -inf) keeps empty-group merges NaN-free.
// ---------------------------------------------------------------------------
__global__ void gat_agg_kernel(const int* __restrict__ rowptr, const int* __restrict__ csr_src,
                               const float* __restrict__ g, const float* __restrict__ a_s,
                               const float* __restrict__ a_d, const float* __restrict__ b2,
                               float* __restrict__ out, int N) {
    const int lane = threadIdx.x & 63;
    const int u = lane & 7, grp = lane >> 3;       // 8 groups x 8 lanes
    const int wib = threadIdx.x >> 6;
    const float4* g4 = (const float4*)g;
    float4* out4 = (float4*)out;
    const float4 b24 = ((const float4*)b2)[u];
    for (int i = blockIdx.x * 4 + wib; i < N; i += gridDim.x * 4) {
        const int b = rowptr[i], e = rowptr[i + 1];
        const float adi = a_d[i];
        float m = -1e30f, ssum = 0.f;
        float ax = 0.f, ay = 0.f, az = 0.f, aw = 0.f;
        for (int j = b + grp; j < e; j += 8) {
            int s = csr_src[j];
            float ev = a_s[s] + adi;
            ev = ev > 0.f ? ev : NEG_SLOPE * ev;
            float mn = fmaxf(m, ev);
            float scale = __expf(m - mn);          // m=-1e30 -> 0 (or 1 if mn still -1e30, state is 0)
            float w = __expf(ev - mn);
            float4 gv = g4[s * 8 + u];
            ssum = ssum * scale + w;
            ax = fmaf(ax, scale, w * gv.x);
            ay = fmaf(ay, scale, w * gv.y);
            az = fmaf(az, scale, w * gv.z);
            aw = fmaf(aw, scale, w * gv.w);
            m = mn;
        }
        // merge 8 group partials (xor 8, 16, 32)
        #pragma unroll
        for (int d = 8; d <= 32; d <<= 1) {
            float mo = __shfl_xor(m, d);
            float so = __shfl_xor(ssum, d);
            float ox = __shfl_xor(ax, d), oy = __shfl_xor(ay, d);
            float oz = __shfl_xor(az, d), ow = __shfl_xor(aw, d);
            float M = fmaxf(m, mo);
            float e0 = __expf(m - M), e1 = __expf(mo - M);
            ssum = ssum * e0 + so * e1;
            ax = ax * e0 + ox * e1; ay = ay * e0 + oy * e1;
            az = az * e0 + oz * e1; aw = aw * e0 + ow * e1;
            m = M;
        }
        if (grp == 0) {
            float inv = 1.f / (ssum + EPS_F);
            float4 o;
            o.x = fmaf(ax, inv, b24.x); o.y = fmaf(ay, inv, b24.y);
            o.z = fmaf(az, inv, b24.z); o.w = fmaf(aw, inv, b24.w);
            out4[(long long)i * 8 + u] = o;
        }
    }
}

extern "C" void kernel_launch(void* const* d_in, const int* in_sizes, int n_in,
                              void* d_out, int out_size, void* d_ws, size_t ws_size,
                              hipStream_t stream) {
    const float* x       = (const float*)d_in[0];
    const int*   ei      = (const int*)d_in[1];   // int32 or int64, detected on device
    const float* W1      = (const float*)d_in[2];
    const float* b1      = (const float*)d_in[3];
    const float* W2      = (const float*)d_in[4];
    const float* att_src = (const float*)d_in[5];
    const float* att_dst = (const float*)d_in[6];
    const float* b2      = (const float*)d_in[7];
    float* out = (float*)d_out;

    const long long N  = in_sizes[0] / D_IN;
    const long long E  = in_sizes[1] / 2;
    const long long E2 = E + N;
    const int NB = (int)((N + SCAN_CHUNK - 1) / SCAN_CHUNK);
    const int K2 = (int)((N + (1 << BKT_SHIFT) - 1) >> BKT_SHIFT);   // 25 for N=100K
    const int EPB = (int)((E2 + NBLK_BIN - 1) / NBLK_BIN);

    // workspace layout (256B aligned slices)
    char* ws = (char*)d_ws;
    size_t off0 = 0;
    auto alloc = [&](size_t bytes) -> void* {
        off0 = (off0 + 255) & ~(size_t)255;
        void* p = ws + off0;
        off0 += bytes;
        return p;
    };
    int*   flag     = (int*)  alloc(16);
    int*   hist     = (int*)  alloc((size_t)KBUKMAX * NBLK_BIN * 4);
    unsigned* bins  = (unsigned*)alloc((size_t)E2 * 4);
    int*   cnt      = (int*)  alloc((size_t)N * 4);
    int*   rowptr   = (int*)  alloc((size_t)(N + 1) * 4);
    int*   csr_src  = (int*)  alloc((size_t)E2 * 4);
    float* dis      = (float*)alloc((size_t)N * 4);
    float* hws      = (float*)alloc((size_t)N * D_HID * 4);
    float* h1       = (float*)alloc((size_t)N * D_HID * 4);
    float* gbuf     = (float*)alloc((size_t)N * D_OUT * 4);
    float* as       = (float*)alloc((size_t)N * 4);
    float* ad       = (float*)alloc((size_t)N * 4);
    int*   blocksum = (int*)  alloc((size_t)NB * 4);
    (void)ws_size; (void)n_in; (void)out_size;

    detect_kernel<<<1, 64, 0, stream>>>(ei, E, flag);
    hist_kernel<<<NBLK_BIN, 256, 0, stream>>>(ei, flag, E, E2, hist, K2, EPB);
    scan_flat_kernel<<<1, 1024, 0, stream>>>(hist, K2 * NBLK_BIN);
    scatter_kernel<<<NBLK_BIN, 256, 0, stream>>>(ei, flag, E, E2, hist, bins, K2, EPB);
    cnt_b_kernel<<<K2, 1024, 0, stream>>>(bins, hist, cnt, (int)N, K2, E2);
    scan_a_kernel<<<NB, 256, 0, stream>>>(cnt, rowptr, dis, blocksum, (int)N);
    scan_b_kernel<<<1, 1024, 0, stream>>>(blocksum, rowptr, NB, (int)N, (int)E2);
    scan_c_kernel<<<(int)((N + 255) / 256), 256, 0, stream>>>(rowptr, blocksum, (int)N);
    fill_b_kernel<<<K2, 1024, 0, stream>>>(bins, hist, rowptr, csr_src, (int)N, K2, E2);
    gemm1_kernel<<<1024, 256, 0, stream>>>(x, W1, dis, hws, (int)N);
    int agg_blocks = (int)((N + 3) / 4);
    gcn_agg_kernel<<<agg_blocks, 256, 0, stream>>>(rowptr, csr_src, hws, dis, b1, h1, (int)N);
    gemm2_kernel<<<1024, 256, 0, stream>>>(h1, W2, att_src, att_dst, gbuf, as, ad, (int)N);
    gat_agg_kernel<<<agg_blocks, 256, 0, stream>>>(rowptr, csr_src, gbuf, as, ad, b2, out, (int)N);
}

// Round 7
// 200.747 us; speedup vs baseline: 6.0765x; 1.3636x over previous
//
#include <hip/hip_runtime.h>
#include <cstdint>
#include <cstddef>

#define D_IN   128
#define D_HID  32
#define D_OUT  32
#define NEG_SLOPE 0.2f
#define EPS_F  1e-16f

#define BKT_SHIFT 9       // 512 nodes per bucket
#define NPB (1 << BKT_SHIFT)
#define KBUKMAX 256       // supports N <= 131072
#define NBLK_BIN 512      // blocks for hist/scatter (runs ~17 entries = 68B, line-dense)

// ---------------------------------------------------------------------------
// edge_index may arrive as int32 or int64. Detect on device: values < 2^17,
// so int64 => every odd int32 word (high half, LE) of the first 64 pairs is 0.
// ---------------------------------------------------------------------------
__global__ void detect_kernel(const int* __restrict__ ei, long long E, int* __restrict__ flag) {
    const int t = threadIdx.x;                     // 64 threads
    long long n = E < 64 ? E : 64;
    int bad = (t < n && ei[2 * t + 1] != 0) ? 1 : 0;
    unsigned long long mask = __ballot(bad);
    if (t == 0) *flag = (mask == 0ULL) ? 1 : 0;
}

__device__ __forceinline__ int edge_val(const int* __restrict__ ei, long long idx, int is64) {
    return is64 ? ei[idx * 2] : ei[idx];
}

// ---------------------------------------------------------------------------
// Multi-split pass 1: per-block bucket histogram (LDS), dense write-out.
// hist layout: [bucket][block] (bucket-major).
// ---------------------------------------------------------------------------
__global__ __launch_bounds__(256) void hist_kernel(
        const int* __restrict__ ei, const int* __restrict__ flag,
        long long E, long long E2, int* __restrict__ hist, int K2, int EPB) {
    __shared__ int hcnt[KBUKMAX];
    const int is64 = *flag;
    const int t = threadIdx.x;
    if (t < K2) hcnt[t] = 0;
    __syncthreads();
    const long long lo = (long long)blockIdx.x * EPB;
    const long long hi = min(E2, lo + EPB);
    for (long long e = lo + t; e < hi; e += 256) {
        int d = (e < E) ? edge_val(ei, E + e, is64) : (int)(e - E);
        atomicAdd(&hcnt[d >> BKT_SHIFT], 1);
    }
    __syncthreads();
    if (t < K2) hist[t * gridDim.x + blockIdx.x] = hcnt[t];
}

// ---------------- generic hierarchical exclusive scan (in-place) ----------
__global__ void scan_ga_kernel(int* __restrict__ a, int* __restrict__ bsum, int L) {
    __shared__ int wsum[4];                        // 256 threads x 4 elems
    const int t = threadIdx.x;
    const int i0 = blockIdx.x * 1024 + t * 4;
    int v[4]; int s = 0;
    #pragma unroll
    for (int k = 0; k < 4; ++k) {
        v[k] = (i0 + k < L) ? a[i0 + k] : 0;
        s += v[k];
    }
    const int lane = t & 63, wid = t >> 6;
    int incl = s;
    #pragma unroll
    for (int d = 1; d < 64; d <<= 1) {
        int u = __shfl_up(incl, d);
        if (lane >= d) incl += u;
    }
    if (lane == 63) wsum[wid] = incl;
    __syncthreads();
    int woff = 0;
    for (int w = 0; w < wid; ++w) woff += wsum[w];
    int excl = woff + incl - s;
    #pragma unroll
    for (int k = 0; k < 4; ++k) {
        if (i0 + k < L) a[i0 + k] = excl;
        excl += v[k];
    }
    if (t == 255) bsum[blockIdx.x] = woff + incl;
}

// single-block exclusive scan (small L)
__global__ __launch_bounds__(1024) void scan_flat_kernel(int* __restrict__ a, int L) {
    __shared__ int wsum[16];
    __shared__ int carry_s;
    const int t = threadIdx.x;
    const int lane = t & 63, wid = t >> 6;
    if (t == 0) carry_s = 0;
    __syncthreads();
    for (int start = 0; start < L; start += 1024) {
        int idx = start + t;
        int v = (idx < L) ? a[idx] : 0;
        int incl = v;
        #pragma unroll
        for (int d = 1; d < 64; d <<= 1) {
            int u = __shfl_up(incl, d);
            if (lane >= d) incl += u;
        }
        if (lane == 63) wsum[wid] = incl;
        __syncthreads();
        int woff = 0;
        for (int w = 0; w < wid; ++w) woff += wsum[w];
        int carry = carry_s;
        __syncthreads();
        if (idx < L) a[idx] = carry + woff + incl - v;
        if (t == 1023) carry_s = carry + woff + incl;
        __syncthreads();
    }
}

__global__ void scan_gc_kernel(int* __restrict__ a, const int* __restrict__ bsum, int L) {
    int idx = blockIdx.x * blockDim.x + threadIdx.x;
    if (idx < L) a[idx] += bsum[idx >> 10];
}

// ---------------------------------------------------------------------------
// Multi-split pass 2: scatter packed (src | dlow<<17) into bins. Each
// (bucket,block) run is block-private & contiguous -> dense writeback.
// ---------------------------------------------------------------------------
__global__ __launch_bounds__(256) void scatter_kernel(
        const int* __restrict__ ei, const int* __restrict__ flag,
        long long E, long long E2, const int* __restrict__ off,
        unsigned* __restrict__ bins, int K2, int EPB) {
    __shared__ int cur[KBUKMAX];
    const int is64 = *flag;
    const int t = threadIdx.x;
    if (t < K2) cur[t] = off[t * gridDim.x + blockIdx.x];
    __syncthreads();
    const long long lo = (long long)blockIdx.x * EPB;
    const long long hi = min(E2, lo + EPB);
    for (long long e = lo + t; e < hi; e += 256) {
        int s, d;
        if (e < E) { s = edge_val(ei, e, is64); d = edge_val(ei, E + e, is64); }
        else       { s = d = (int)(e - E); }
        int b = d >> BKT_SHIFT;
        int pos = atomicAdd(&cur[b], 1);
        bins[pos] = (unsigned)s | ((unsigned)(d & (NPB - 1)) << 17);
    }
}

// ---------------------------------------------------------------------------
// Fused CSR build, one block per 512-node bucket. Key identity: the bucket's
// CSR window == its bins window (CSR ordered by dst, buckets are dst-ranges),
// so rowptr = bucket_base + local_excl_scan(local_counts). Deletes the global
// cnt array, its N-wide scan, and the separate fill pass.
// ---------------------------------------------------------------------------
__global__ __launch_bounds__(512) void csr_b_kernel(
        const unsigned* __restrict__ bins, const int* __restrict__ off,
        int* __restrict__ rowptr, float* __restrict__ dis, int* __restrict__ csr_src,
        int N, int K2, long long E2) {
    __shared__ int lcur[NPB];
    __shared__ int wsum[8];
    const int b = blockIdx.x, t = threadIdx.x;     // 512 threads
    const int nbase = b << BKT_SHIFT;
    const int nn = min(NPB, N - nbase);
    lcur[t] = 0;
    __syncthreads();
    const int base = off[b * NBLK_BIN];
    const int end  = (b == K2 - 1) ? (int)E2 : off[(b + 1) * NBLK_BIN];
    // pass 1: local degree count
    for (int i = base + t; i < end; i += 512)
        atomicAdd(&lcur[bins[i] >> 17], 1);
    __syncthreads();
    // 512-wide exclusive scan of lcur
    const int lane = t & 63, wid = t >> 6;
    int v = lcur[t];
    int incl = v;
    #pragma unroll
    for (int d = 1; d < 64; d <<= 1) {
        int u = __shfl_up(incl, d);
        if (lane >= d) incl += u;
    }
    if (lane == 63) wsum[wid] = incl;
    __syncthreads();
    int woff = 0;
    for (int w = 0; w < wid; ++w) woff += wsum[w];
    int excl = woff + incl - v;
    if (t < nn) {
        rowptr[nbase + t] = base + excl;
        dis[nbase + t] = rsqrtf((float)v);         // deg >= 1 (self-loop)
    }
    __syncthreads();                               // lcur reuse hazard
    lcur[t] = base + excl;
    __syncthreads();
    // pass 2: scatter into this bucket's contiguous CSR window
    for (int i = base + t; i < end; i += 512) {
        unsigned u = bins[i];
        int pos = atomicAdd(&lcur[u >> 17], 1);
        csr_src[pos] = (int)(u & 0x1FFFFu);
    }
    if (b == 0 && t == 0) rowptr[N] = (int)E2;
}

// hws[i][:] = dis[i] * (x[i] @ W1)      (pre-scaled so GCN gather needs no dis[src])
__global__ void gemm1_kernel(const float* __restrict__ x, const float* __restrict__ W1,
                             const float* __restrict__ dis, float* __restrict__ hws, int N) {
    __shared__ float sW[D_IN * D_HID];      // 16 KB
    __shared__ float sx[8][D_IN];           // 4 KB
    const int t = threadIdx.x;              // 256
    const int c = t & 31, r = t >> 5;
    for (int i = t; i < D_IN * D_HID; i += 256) sW[i] = W1[i];
    for (long long base = (long long)blockIdx.x * 8; base < N; base += (long long)gridDim.x * 8) {
        __syncthreads();
        if (base + 8 <= N) {
            const float4* xp = (const float4*)(x + base * D_IN);
            float4 v = xp[t];
            sx[t >> 5][(t & 31) * 4 + 0] = v.x;
            sx[t >> 5][(t & 31) * 4 + 1] = v.y;
            sx[t >> 5][(t & 31) * 4 + 2] = v.z;
            sx[t >> 5][(t & 31) * 4 + 3] = v.w;
        } else {
            long long nrem = (N - base) * D_IN;
            for (int i = t; i < nrem; i += 256) sx[i >> 7][i & 127] = x[base * D_IN + i];
        }
        __syncthreads();
        long long row = base + r;
        if (row < N) {
            float acc = 0.0f;
            #pragma unroll 16
            for (int k = 0; k < D_IN; ++k) acc = fmaf(sx[r][k], sW[k * D_HID + c], acc);
            hws[row * D_HID + c] = acc * dis[row];
        }
    }
}

// ---------------------------------------------------------------------------
// GCN aggregate + bias + ReLU. 8 edges in flight per wave: 8 groups x 8
// lanes, each lane holds float4 of the 32-float row (8x16B = 128B/edge).
// ---------------------------------------------------------------------------
__global__ void gcn_agg_kernel(const int* __restrict__ rowptr, const int* __restrict__ csr_src,
                               const float* __restrict__ hws, const float* __restrict__ dis,
                               const float* __restrict__ b1, float* __restrict__ h1, int N) {
    const int lane = threadIdx.x & 63;
    const int u = lane & 7, grp = lane >> 3;       // 8 groups x 8 lanes
    const int wib = threadIdx.x >> 6;              // 4 waves / block
    const float4* hws4 = (const float4*)hws;
    float4* h14 = (float4*)h1;
    const float4 b14 = ((const float4*)b1)[u];
    for (int i = blockIdx.x * 4 + wib; i < N; i += gridDim.x * 4) {
        const int b = rowptr[i], e = rowptr[i + 1];
        float ax = 0.f, ay = 0.f, az = 0.f, aw = 0.f;
        for (int j = b + grp; j < e; j += 8) {
            int s = csr_src[j];
            float4 hv = hws4[s * 8 + u];
            ax += hv.x; ay += hv.y; az += hv.z; aw += hv.w;
        }
        #pragma unroll
        for (int d = 8; d <= 32; d <<= 1) {
            ax += __shfl_xor(ax, d); ay += __shfl_xor(ay, d);
            az += __shfl_xor(az, d); aw += __shfl_xor(aw, d);
        }
        if (grp == 0) {
            float dd = dis[i];
            float4 o;
            o.x = fmaf(dd, ax, b14.x); o.y = fmaf(dd, ay, b14.y);
            o.z = fmaf(dd, az, b14.z); o.w = fmaf(dd, aw, b14.w);
            o.x = o.x > 0.f ? o.x : 0.f; o.y = o.y > 0.f ? o.y : 0.f;
            o.z = o.z > 0.f ? o.z : 0.f; o.w = o.w > 0.f ? o.w : 0.f;
            h14[(long long)i * 8 + u] = o;
        }
    }
}

// g = h1 @ W2 ; a_s = g @ att_src ; a_d = g @ att_dst
__global__ void gemm2_kernel(const float* __restrict__ h1, const float* __restrict__ W2,
                             const float* __restrict__ att_s, const float* __restrict__ att_d,
                             float* __restrict__ g, float* __restrict__ a_s, float* __restrict__ a_d,
                             int N) {
    __shared__ float sW[D_HID * D_OUT];     // 4 KB
    __shared__ float sas[D_OUT], sad[D_OUT];
    __shared__ float sh[8][D_HID];          // 1 KB
    const int t = threadIdx.x;              // 256
    const int c = t & 31, r = t >> 5;
    for (int i = t; i < D_HID * D_OUT; i += 256) sW[i] = W2[i];
    if (t < D_OUT) { sas[t] = att_s[t]; sad[t] = att_d[t]; }
    for (long long base = (long long)blockIdx.x * 8; base < N; base += (long long)gridDim.x * 8) {
        __syncthreads();
        if (base * D_HID + t < (long long)N * D_HID) sh[r][c] = h1[base * D_HID + t];
        __syncthreads();
        long long row = base + r;
        if (row < N) {
            float gv = 0.0f;
            #pragma unroll
            for (int k = 0; k < D_HID; ++k) gv = fmaf(sh[r][k], sW[k * D_OUT + c], gv);
            g[row * D_OUT + c] = gv;
            float ps = gv * sas[c];
            float pd = gv * sad[c];
            #pragma unroll
            for (int d = 16; d >= 1; d >>= 1) {
                ps += __shfl_xor(ps, d);
                pd += __shfl_xor(pd, d);
            }
            if (c == 0) { a_s[row] = ps; a_d[row] = pd; }
        }
    }
}

// ---------------------------------------------------------------------------
// GAT aggregate, online segment-softmax, 8 edges in flight per wave.
// Finite sentinel -1e30 (not -inf) keeps empty-group merges NaN-free.
// ---------------------------------------------------------------------------
__global__ void gat_agg_kernel(const int* __restrict__ rowptr, const int* __restrict__ csr_src,
                               const float* __restrict__ g, const float* __restrict__ a_s,
                               const float* __restrict__ a_d, const float* __restrict__ b2,
                               float* __restrict__ out, int N) {
    const int lane = threadIdx.x & 63;
    const int u = lane & 7, grp = lane >> 3;       // 8 groups x 8 lanes
    const int wib = threadIdx.x >> 6;
    const float4* g4 = (const float4*)g;
    float4* out4 = (float4*)out;
    const float4 b24 = ((const float4*)b2)[u];
    for (int i = blockIdx.x * 4 + wib; i < N; i += gridDim.x * 4) {
        const int b = rowptr[i], e = rowptr[i + 1];
        const float adi = a_d[i];
        float m = -1e30f, ssum = 0.f;
        float ax = 0.f, ay = 0.f, az = 0.f, aw = 0.f;
        for (int j = b + grp; j < e; j += 8) {
            int s = csr_src[j];
            float ev = a_s[s] + adi;
            ev = ev > 0.f ? ev : NEG_SLOPE * ev;
            float mn = fmaxf(m, ev);
            float scale = __expf(m - mn);
            float w = __expf(ev - mn);
            float4 gv = g4[s * 8 + u];
            ssum = ssum * scale + w;
            ax = fmaf(ax, scale, w * gv.x);
            ay = fmaf(ay, scale, w * gv.y);
            az = fmaf(az, scale, w * gv.z);
            aw = fmaf(aw, scale, w * gv.w);
            m = mn;
        }
        #pragma unroll
        for (int d = 8; d <= 32; d <<= 1) {
            float mo = __shfl_xor(m, d);
            float so = __shfl_xor(ssum, d);
            float ox = __shfl_xor(ax, d), oy = __shfl_xor(ay, d);
            float oz = __shfl_xor(az, d), ow = __shfl_xor(aw, d);
            float M = fmaxf(m, mo);
            float e0 = __expf(m - M), e1 = __expf(mo - M);
            ssum = ssum * e0 + so * e1;
            ax = ax * e0 + ox * e1; ay = ay * e0 + oy * e1;
            az = az * e0 + oz * e1; aw = aw * e0 + ow * e1;
            m = M;
        }
        if (grp == 0) {
            float inv = 1.f / (ssum + EPS_F);
            float4 o;
            o.x = fmaf(ax, inv, b24.x); o.y = fmaf(ay, inv, b24.y);
            o.z = fmaf(az, inv, b24.z); o.w = fmaf(aw, inv, b24.w);
            out4[(long long)i * 8 + u] = o;
        }
    }
}

extern "C" void kernel_launch(void* const* d_in, const int* in_sizes, int n_in,
                              void* d_out, int out_size, void* d_ws, size_t ws_size,
                              hipStream_t stream) {
    const float* x       = (const float*)d_in[0];
    const int*   ei      = (const int*)d_in[1];   // int32 or int64, detected on device
    const float* W1      = (const float*)d_in[2];
    const float* b1      = (const float*)d_in[3];
    const float* W2      = (const float*)d_in[4];
    const float* att_src = (const float*)d_in[5];
    const float* att_dst = (const float*)d_in[6];
    const float* b2      = (const float*)d_in[7];
    float* out = (float*)d_out;

    const long long N  = in_sizes[0] / D_IN;
    const long long E  = in_sizes[1] / 2;
    const long long E2 = E + N;
    const int K2  = (int)((N + NPB - 1) >> BKT_SHIFT);              // 196 for N=100K
    const int EPB = (int)((E2 + NBLK_BIN - 1) / NBLK_BIN);
    const int LH  = K2 * NBLK_BIN;                                  // hist length
    const int NBH = (LH + 1023) / 1024;                             // hist scan blocks

    // workspace layout (256B aligned slices)
    char* ws = (char*)d_ws;
    size_t off0 = 0;
    auto alloc = [&](size_t bytes) -> void* {
        off0 = (off0 + 255) & ~(size_t)255;
        void* p = ws + off0;
        off0 += bytes;
        return p;
    };
    int*   flag     = (int*)  alloc(16);
    int*   hist     = (int*)  alloc((size_t)KBUKMAX * NBLK_BIN * 4);
    unsigned* bins  = (unsigned*)alloc((size_t)E2 * 4);
    int*   rowptr   = (int*)  alloc((size_t)(N + 1) * 4);
    int*   csr_src  = (int*)  alloc((size_t)E2 * 4);
    float* dis      = (float*)alloc((size_t)N * 4);
    float* hws      = (float*)alloc((size_t)N * D_HID * 4);
    float* h1       = (float*)alloc((size_t)N * D_HID * 4);
    float* gbuf     = (float*)alloc((size_t)N * D_OUT * 4);
    float* as       = (float*)alloc((size_t)N * 4);
    float* ad       = (float*)alloc((size_t)N * 4);
    int*   bsum     = (int*)  alloc((size_t)NBH * 4);
    (void)ws_size; (void)n_in; (void)out_size;

    detect_kernel<<<1, 64, 0, stream>>>(ei, E, flag);
    hist_kernel<<<NBLK_BIN, 256, 0, stream>>>(ei, flag, E, E2, hist, K2, EPB);
    scan_ga_kernel<<<NBH, 256, 0, stream>>>(hist, bsum, LH);
    scan_flat_kernel<<<1, 1024, 0, stream>>>(bsum, NBH);
    scan_gc_kernel<<<(LH + 255) / 256, 256, 0, stream>>>(hist, bsum, LH);
    scatter_kernel<<<NBLK_BIN, 256, 0, stream>>>(ei, flag, E, E2, hist, bins, K2, EPB);
    csr_b_kernel<<<K2, 512, 0, stream>>>(bins, hist, rowptr, dis, csr_src, (int)N, K2, E2);
    gemm1_kernel<<<1024, 256, 0, stream>>>(x, W1, dis, hws, (int)N);
    int agg_blocks = (int)((N + 3) / 4);
    gcn_agg_kernel<<<agg_blocks, 256, 0, stream>>>(rowptr, csr_src, hws, dis, b1, h1, (int)N);
    gemm2_kernel<<<1024, 256, 0, stream>>>(h1, W2, att_src, att_dst, gbuf, as, ad, (int)N);
    gat_agg_kernel<<<agg_blocks, 256, 0, stream>>>(rowptr, csr_src, gbuf, as, ad, b2, out, (int)N);
}

// Round 8
// 187.155 us; speedup vs baseline: 6.5178x; 1.0726x over previous
//
#include <hip/hip_runtime.h>
#include <cstdint>
#include <cstddef>

#define D_IN   128
#define D_HID  32
#define D_OUT  32
#define NEG_SLOPE 0.2f
#define EPS_F  1e-16f

#define BKT_SHIFT 9       // 512 nodes per bucket
#define NPB (1 << BKT_SHIFT)
#define KBUKMAX 256       // supports N <= 131072
#define NBLK_BIN 512      // blocks for hist/scatter (runs ~17 entries = 68B, line-dense)

// ---------------------------------------------------------------------------
// edge_index may arrive as int32 or int64. Detect on device: values < 2^17,
// so int64 => every odd int32 word (high half, LE) of the first 64 pairs is 0.
// ---------------------------------------------------------------------------
__global__ void detect_kernel(const int* __restrict__ ei, long long E, int* __restrict__ flag) {
    const int t = threadIdx.x;                     // 64 threads
    long long n = E < 64 ? E : 64;
    int bad = (t < n && ei[2 * t + 1] != 0) ? 1 : 0;
    unsigned long long mask = __ballot(bad);
    if (t == 0) *flag = (mask == 0ULL) ? 1 : 0;
}

__device__ __forceinline__ int edge_val(const int* __restrict__ ei, long long idx, int is64) {
    return is64 ? ei[idx * 2] : ei[idx];
}

// ---------------------------------------------------------------------------
// Multi-split pass 1: per-block bucket histogram (LDS), dense write-out.
// hist layout: [bucket][block] (bucket-major).
// ---------------------------------------------------------------------------
__global__ __launch_bounds__(256) void hist_kernel(
        const int* __restrict__ ei, const int* __restrict__ flag,
        long long E, long long E2, int* __restrict__ hist, int K2, int EPB) {
    __shared__ int hcnt[KBUKMAX];
    const int is64 = *flag;
    const int t = threadIdx.x;
    if (t < K2) hcnt[t] = 0;
    __syncthreads();
    const long long lo = (long long)blockIdx.x * EPB;
    const long long hi = min(E2, lo + EPB);
    for (long long e = lo + t; e < hi; e += 256) {
        int d = (e < E) ? edge_val(ei, E + e, is64) : (int)(e - E);
        atomicAdd(&hcnt[d >> BKT_SHIFT], 1);
    }
    __syncthreads();
    if (t < K2) hist[t * gridDim.x + blockIdx.x] = hcnt[t];
}

// ---------------- generic hierarchical exclusive scan (in-place) ----------
__global__ void scan_ga_kernel(int* __restrict__ a, int* __restrict__ bsum, int L) {
    __shared__ int wsum[4];                        // 256 threads x 4 elems
    const int t = threadIdx.x;
    const int i0 = blockIdx.x * 1024 + t * 4;
    int v[4]; int s = 0;
    #pragma unroll
    for (int k = 0; k < 4; ++k) {
        v[k] = (i0 + k < L) ? a[i0 + k] : 0;
        s += v[k];
    }
    const int lane = t & 63, wid = t >> 6;
    int incl = s;
    #pragma unroll
    for (int d = 1; d < 64; d <<= 1) {
        int u = __shfl_up(incl, d);
        if (lane >= d) incl += u;
    }
    if (lane == 63) wsum[wid] = incl;
    __syncthreads();
    int woff = 0;
    for (int w = 0; w < wid; ++w) woff += wsum[w];
    int excl = woff + incl - s;
    #pragma unroll
    for (int k = 0; k < 4; ++k) {
        if (i0 + k < L) a[i0 + k] = excl;
        excl += v[k];
    }
    if (t == 255) bsum[blockIdx.x] = woff + incl;
}

// single-block exclusive scan (small L)
__global__ __launch_bounds__(1024) void scan_flat_kernel(int* __restrict__ a, int L) {
    __shared__ int wsum[16];
    __shared__ int carry_s;
    const int t = threadIdx.x;
    const int lane = t & 63, wid = t >> 6;
    if (t == 0) carry_s = 0;
    __syncthreads();
    for (int start = 0; start < L; start += 1024) {
        int idx = start + t;
        int v = (idx < L) ? a[idx] : 0;
        int incl = v;
        #pragma unroll
        for (int d = 1; d < 64; d <<= 1) {
            int u = __shfl_up(incl, d);
            if (lane >= d) incl += u;
        }
        if (lane == 63) wsum[wid] = incl;
        __syncthreads();
        int woff = 0;
        for (int w = 0; w < wid; ++w) woff += wsum[w];
        int carry = carry_s;
        __syncthreads();
        if (idx < L) a[idx] = carry + woff + incl - v;
        if (t == 1023) carry_s = carry + woff + incl;
        __syncthreads();
    }
}

__global__ void scan_gc_kernel(int* __restrict__ a, const int* __restrict__ bsum, int L) {
    int idx = blockIdx.x * blockDim.x + threadIdx.x;
    if (idx < L) a[idx] += bsum[idx >> 10];
}

// ---------------------------------------------------------------------------
// Multi-split pass 2: scatter packed (src | dlow<<17) into bins. Each
// (bucket,block) run is block-private & contiguous -> dense writeback.
// ---------------------------------------------------------------------------
__global__ __launch_bounds__(256) void scatter_kernel(
        const int* __restrict__ ei, const int* __restrict__ flag,
        long long E, long long E2, const int* __restrict__ off,
        unsigned* __restrict__ bins, int K2, int EPB) {
    __shared__ int cur[KBUKMAX];
    const int is64 = *flag;
    const int t = threadIdx.x;
    if (t < K2) cur[t] = off[t * gridDim.x + blockIdx.x];
    __syncthreads();
    const long long lo = (long long)blockIdx.x * EPB;
    const long long hi = min(E2, lo + EPB);
    for (long long e = lo + t; e < hi; e += 256) {
        int s, d;
        if (e < E) { s = edge_val(ei, e, is64); d = edge_val(ei, E + e, is64); }
        else       { s = d = (int)(e - E); }
        int b = d >> BKT_SHIFT;
        int pos = atomicAdd(&cur[b], 1);
        bins[pos] = (unsigned)s | ((unsigned)(d & (NPB - 1)) << 17);
    }
}

// ---------------------------------------------------------------------------
// Fused CSR build, one block per 512-node bucket. Key identity: the bucket's
// CSR window == its bins window (CSR ordered by dst, buckets are dst-ranges),
// so rowptr = bucket_base + local_excl_scan(local_counts).
// ---------------------------------------------------------------------------
__global__ __launch_bounds__(512) void csr_b_kernel(
        const unsigned* __restrict__ bins, const int* __restrict__ off,
        int* __restrict__ rowptr, float* __restrict__ dis, int* __restrict__ csr_src,
        int N, int K2, long long E2) {
    __shared__ int lcur[NPB];
    __shared__ int wsum[8];
    const int b = blockIdx.x, t = threadIdx.x;     // 512 threads
    const int nbase = b << BKT_SHIFT;
    const int nn = min(NPB, N - nbase);
    lcur[t] = 0;
    __syncthreads();
    const int base = off[b * NBLK_BIN];
    const int end  = (b == K2 - 1) ? (int)E2 : off[(b + 1) * NBLK_BIN];
    // pass 1: local degree count
    for (int i = base + t; i < end; i += 512)
        atomicAdd(&lcur[bins[i] >> 17], 1);
    __syncthreads();
    // 512-wide exclusive scan of lcur
    const int lane = t & 63, wid = t >> 6;
    int v = lcur[t];
    int incl = v;
    #pragma unroll
    for (int d = 1; d < 64; d <<= 1) {
        int u = __shfl_up(incl, d);
        if (lane >= d) incl += u;
    }
    if (lane == 63) wsum[wid] = incl;
    __syncthreads();
    int woff = 0;
    for (int w = 0; w < wid; ++w) woff += wsum[w];
    int excl = woff + incl - v;
    if (t < nn) {
        rowptr[nbase + t] = base + excl;
        dis[nbase + t] = rsqrtf((float)v);         // deg >= 1 (self-loop)
    }
    __syncthreads();                               // lcur reuse hazard
    lcur[t] = base + excl;
    __syncthreads();
    // pass 2: scatter into this bucket's contiguous CSR window
    for (int i = base + t; i < end; i += 512) {
        unsigned u = bins[i];
        int pos = atomicAdd(&lcur[u >> 17], 1);
        csr_src[pos] = (int)(u & 0x1FFFFu);
    }
    if (b == 0 && t == 0) rowptr[N] = (int)E2;
}

// ---------------------------------------------------------------------------
// gemm1 v2: register-tiled. hws[i][:] = dis[i] * (x[i] @ W1).
// 4 rows x 4 cols x float4-k per thread; W1 transposed in LDS (padded);
// x streamed from global (same-address lanes coalesce; each row read once).
// Per k-quad: 4 LDS b128 + 4 global b128 serve 64 FMAs (was 2 b32 per FMA).
// ---------------------------------------------------------------------------
__global__ __launch_bounds__(256) void gemm1_kernel(
        const float* __restrict__ x, const float* __restrict__ W1,
        const float* __restrict__ dis, float* __restrict__ hws, int N) {
    __shared__ float sWt[D_HID][D_IN + 4];         // transposed, +4 pad
    const int t = threadIdx.x;
    for (int i = t; i < D_IN * D_HID; i += 256) {
        int k = i >> 5, c = i & 31;
        sWt[c][k] = W1[i];
    }
    __syncthreads();
    const int c_t = t & 7;                         // 8 col-groups of 4
    const int r_t = t >> 3;                        // 32 row-threads of 4
    const long long row0 = (long long)blockIdx.x * 128 + (long long)r_t * 4;
    const float4* x4 = (const float4*)x;
    float acc[4][4];
    #pragma unroll
    for (int i = 0; i < 4; ++i)
        #pragma unroll
        for (int j = 0; j < 4; ++j) acc[i][j] = 0.f;
    long long r[4]; bool val[4];
    #pragma unroll
    for (int i = 0; i < 4; ++i) {
        long long rr = row0 + i;
        val[i] = rr < N;
        r[i] = val[i] ? rr : (long long)(N - 1);
    }
    #pragma unroll 4
    for (int q = 0; q < 32; ++q) {
        float4 wv[4];
        #pragma unroll
        for (int j = 0; j < 4; ++j)
            wv[j] = *(const float4*)&sWt[c_t * 4 + j][q * 4];
        #pragma unroll
        for (int i = 0; i < 4; ++i) {
            float4 xv = x4[r[i] * 32 + q];
            #pragma unroll
            for (int j = 0; j < 4; ++j) {
                acc[i][j] = fmaf(xv.x, wv[j].x, acc[i][j]);
                acc[i][j] = fmaf(xv.y, wv[j].y, acc[i][j]);
                acc[i][j] = fmaf(xv.z, wv[j].z, acc[i][j]);
                acc[i][j] = fmaf(xv.w, wv[j].w, acc[i][j]);
            }
        }
    }
    float4* hws4 = (float4*)hws;
    #pragma unroll
    for (int i = 0; i < 4; ++i) {
        if (val[i]) {
            float dd = dis[r[i]];
            float4 o;
            o.x = acc[i][0] * dd; o.y = acc[i][1] * dd;
            o.z = acc[i][2] * dd; o.w = acc[i][3] * dd;
            hws4[r[i] * 8 + c_t] = o;
        }
    }
}

// ---------------------------------------------------------------------------
// GCN aggregate + bias + ReLU. 8 edges in flight per wave: 8 groups x 8
// lanes, each lane holds float4 of the 32-float row (8x16B = 128B/edge).
// ---------------------------------------------------------------------------
__global__ void gcn_agg_kernel(const int* __restrict__ rowptr, const int* __restrict__ csr_src,
                               const float* __restrict__ hws, const float* __restrict__ dis,
                               const float* __restrict__ b1, float* __restrict__ h1, int N) {
    const int lane = threadIdx.x & 63;
    const int u = lane & 7, grp = lane >> 3;       // 8 groups x 8 lanes
    const int wib = threadIdx.x >> 6;              // 4 waves / block
    const float4* hws4 = (const float4*)hws;
    float4* h14 = (float4*)h1;
    const float4 b14 = ((const float4*)b1)[u];
    for (int i = blockIdx.x * 4 + wib; i < N; i += gridDim.x * 4) {
        const int b = rowptr[i], e = rowptr[i + 1];
        float ax = 0.f, ay = 0.f, az = 0.f, aw = 0.f;
        for (int j = b + grp; j < e; j += 8) {
            int s = csr_src[j];
            float4 hv = hws4[s * 8 + u];
            ax += hv.x; ay += hv.y; az += hv.z; aw += hv.w;
        }
        #pragma unroll
        for (int d = 8; d <= 32; d <<= 1) {
            ax += __shfl_xor(ax, d); ay += __shfl_xor(ay, d);
            az += __shfl_xor(az, d); aw += __shfl_xor(aw, d);
        }
        if (grp == 0) {
            float dd = dis[i];
            float4 o;
            o.x = fmaf(dd, ax, b14.x); o.y = fmaf(dd, ay, b14.y);
            o.z = fmaf(dd, az, b14.z); o.w = fmaf(dd, aw, b14.w);
            o.x = o.x > 0.f ? o.x : 0.f; o.y = o.y > 0.f ? o.y : 0.f;
            o.z = o.z > 0.f ? o.z : 0.f; o.w = o.w > 0.f ? o.w : 0.f;
            h14[(long long)i * 8 + u] = o;
        }
    }
}

// g = h1 @ W2 ; a_s = g @ att_src ; a_d = g @ att_dst
__global__ void gemm2_kernel(const float* __restrict__ h1, const float* __restrict__ W2,
                             const float* __restrict__ att_s, const float* __restrict__ att_d,
                             float* __restrict__ g, float* __restrict__ a_s, float* __restrict__ a_d,
                             int N) {
    __shared__ float sW[D_HID * D_OUT];     // 4 KB
    __shared__ float sas[D_OUT], sad[D_OUT];
    __shared__ float sh[8][D_HID];          // 1 KB
    const int t = threadIdx.x;              // 256
    const int c = t & 31, r = t >> 5;
    for (int i = t; i < D_HID * D_OUT; i += 256) sW[i] = W2[i];
    if (t < D_OUT) { sas[t] = att_s[t]; sad[t] = att_d[t]; }
    for (long long base = (long long)blockIdx.x * 8; base < N; base += (long long)gridDim.x * 8) {
        __syncthreads();
        if (base * D_HID + t < (long long)N * D_HID) sh[r][c] = h1[base * D_HID + t];
        __syncthreads();
        long long row = base + r;
        if (row < N) {
            float gv = 0.0f;
            #pragma unroll
            for (int k = 0; k < D_HID; ++k) gv = fmaf(sh[r][k], sW[k * D_OUT + c], gv);
            g[row * D_OUT + c] = gv;
            float ps = gv * sas[c];
            float pd = gv * sad[c];
            #pragma unroll
            for (int d = 16; d >= 1; d >>= 1) {
                ps += __shfl_xor(ps, d);
                pd += __shfl_xor(pd, d);
            }
            if (c == 0) { a_s[row] = ps; a_d[row] = pd; }
        }
    }
}

// ---------------------------------------------------------------------------
// GAT aggregate, online segment-softmax, 8 edges in flight per wave.
// ---------------------------------------------------------------------------
__global__ void gat_agg_kernel(const int* __restrict__ rowptr, const int* __restrict__ csr_src,
                               const float* __restrict__ g, const float* __restrict__ a_s,
                               const float* __restrict__ a_d, const float* __restrict__ b2,
                               float* __restrict__ out, int N) {
    const int lane = threadIdx.x & 63;
    const int u = lane & 7, grp = lane >> 3;       // 8 groups x 8 lanes
    const int wib = threadIdx.x >> 6;
    const float4* g4 = (const float4*)g;
    float4* out4 = (float4*)out;
    const float4 b24 = ((const float4*)b2)[u];
    for (int i = blockIdx.x * 4 + wib; i < N; i += gridDim.x * 4) {
        const int b = rowptr[i], e = rowptr[i + 1];
        const float adi = a_d[i];
        float m = -1e30f, ssum = 0.f;
        float ax = 0.f, ay = 0.f, az = 0.f, aw = 0.f;
        for (int j = b + grp; j < e; j += 8) {
            int s = csr_src[j];
            float ev = a_s[s] + adi;
            ev = ev > 0.f ? ev : NEG_SLOPE * ev;
            float mn = fmaxf(m, ev);
            float scale = __expf(m - mn);
            float w = __expf(ev - mn);
            float4 gv = g4[s * 8 + u];
            ssum = ssum * scale + w;
            ax = fmaf(ax, scale, w * gv.x);
            ay = fmaf(ay, scale, w * gv.y);
            az = fmaf(az, scale, w * gv.z);
            aw = fmaf(aw, scale, w * gv.w);
            m = mn;
        }
        #pragma unroll
        for (int d = 8; d <= 32; d <<= 1) {
            float mo = __shfl_xor(m, d);
            float so = __shfl_xor(ssum, d);
            float ox = __shfl_xor(ax, d), oy = __shfl_xor(ay, d);
            float oz = __shfl_xor(az, d), ow = __shfl_xor(aw, d);
            float M = fmaxf(m, mo);
            float e0 = __expf(m - M), e1 = __expf(mo - M);
            ssum = ssum * e0 + so * e1;
            ax = ax * e0 + ox * e1; ay = ay * e0 + oy * e1;
            az = az * e0 + oz * e1; aw = aw * e0 + ow * e1;
            m = M;
        }
        if (grp == 0) {
            float inv = 1.f / (ssum + EPS_F);
            float4 o;
            o.x = fmaf(ax, inv, b24.x); o.y = fmaf(ay, inv, b24.y);
            o.z = fmaf(az, inv, b24.z); o.w = fmaf(aw, inv, b24.w);
            out4[(long long)i * 8 + u] = o;
        }
    }
}

extern "C" void kernel_launch(void* const* d_in, const int* in_sizes, int n_in,
                              void* d_out, int out_size, void* d_ws, size_t ws_size,
                              hipStream_t stream) {
    const float* x       = (const float*)d_in[0];
    const int*   ei      = (const int*)d_in[1];   // int32 or int64, detected on device
    const float* W1      = (const float*)d_in[2];
    const float* b1      = (const float*)d_in[3];
    const float* W2      = (const float*)d_in[4];
    const float* att_src = (const float*)d_in[5];
    const float* att_dst = (const float*)d_in[6];
    const float* b2      = (const float*)d_in[7];
    float* out = (float*)d_out;

    const long long N  = in_sizes[0] / D_IN;
    const long long E  = in_sizes[1] / 2;
    const long long E2 = E + N;
    const int K2  = (int)((N + NPB - 1) >> BKT_SHIFT);              // 196 for N=100K
    const int EPB = (int)((E2 + NBLK_BIN - 1) / NBLK_BIN);
    const int LH  = K2 * NBLK_BIN;                                  // hist length
    const int NBH = (LH + 1023) / 1024;                             // hist scan blocks

    // workspace layout (256B aligned slices)
    char* ws = (char*)d_ws;
    size_t off0 = 0;
    auto alloc = [&](size_t bytes) -> void* {
        off0 = (off0 + 255) & ~(size_t)255;
        void* p = ws + off0;
        off0 += bytes;
        return p;
    };
    int*   flag     = (int*)  alloc(16);
    int*   hist     = (int*)  alloc((size_t)KBUKMAX * NBLK_BIN * 4);
    unsigned* bins  = (unsigned*)alloc((size_t)E2 * 4);
    int*   rowptr   = (int*)  alloc((size_t)(N + 1) * 4);
    int*   csr_src  = (int*)  alloc((size_t)E2 * 4);
    float* dis      = (float*)alloc((size_t)N * 4);
    float* hws      = (float*)alloc((size_t)N * D_HID * 4);
    float* h1       = (float*)alloc((size_t)N * D_HID * 4);
    float* gbuf     = (float*)alloc((size_t)N * D_OUT * 4);
    float* as       = (float*)alloc((size_t)N * 4);
    float* ad       = (float*)alloc((size_t)N * 4);
    int*   bsum     = (int*)  alloc((size_t)NBH * 4);
    (void)ws_size; (void)n_in; (void)out_size;

    detect_kernel<<<1, 64, 0, stream>>>(ei, E, flag);
    hist_kernel<<<NBLK_BIN, 256, 0, stream>>>(ei, flag, E, E2, hist, K2, EPB);
    scan_ga_kernel<<<NBH, 256, 0, stream>>>(hist, bsum, LH);
    scan_flat_kernel<<<1, 1024, 0, stream>>>(bsum, NBH);
    scan_gc_kernel<<<(LH + 255) / 256, 256, 0, stream>>>(hist, bsum, LH);
    scatter_kernel<<<NBLK_BIN, 256, 0, stream>>>(ei, flag, E, E2, hist, bins, K2, EPB);
    csr_b_kernel<<<K2, 512, 0, stream>>>(bins, hist, rowptr, dis, csr_src, (int)N, K2, E2);
    gemm1_kernel<<<(int)((N + 127) / 128), 256, 0, stream>>>(x, W1, dis, hws, (int)N);
    int agg_blocks = (int)((N + 3) / 4);
    gcn_agg_kernel<<<agg_blocks, 256, 0, stream>>>(rowptr, csr_src, hws, dis, b1, h1, (int)N);
    gemm2_kernel<<<1024, 256, 0, stream>>>(h1, W2, att_src, att_dst, gbuf, as, ad, (int)N);
    gat_agg_kernel<<<agg_blocks, 256, 0, stream>>>(rowptr, csr_src, gbuf, as, ad, b2, out, (int)N);
}

// Round 9
// 185.339 us; speedup vs baseline: 6.5817x; 1.0098x over previous
//
#include <hip/hip_runtime.h>
#include <cstdint>
#include <cstddef>

#define D_IN   128
#define D_HID  32
#define D_OUT  32
#define NEG_SLOPE 0.2f
#define EPS_F  1e-16f

#define BKT_SHIFT 9       // 512 nodes per bucket
#define NPB (1 << BKT_SHIFT)
#define KBUKMAX 256       // supports N <= 131072
#define NBLK_BIN 512      // blocks for hist/scatter (runs ~17 entries = 68B, line-dense)

using half4 = __attribute__((ext_vector_type(4))) _Float16;

// ---------------------------------------------------------------------------
// edge_index may arrive as int32 or int64. Detect on device: values < 2^17,
// so int64 => every odd int32 word (high half, LE) of the first 64 pairs is 0.
// ---------------------------------------------------------------------------
__global__ void detect_kernel(const int* __restrict__ ei, long long E, int* __restrict__ flag) {
    const int t = threadIdx.x;                     // 64 threads
    long long n = E < 64 ? E : 64;
    int bad = (t < n && ei[2 * t + 1] != 0) ? 1 : 0;
    unsigned long long mask = __ballot(bad);
    if (t == 0) *flag = (mask == 0ULL) ? 1 : 0;
}

__device__ __forceinline__ int edge_val(const int* __restrict__ ei, long long idx, int is64) {
    return is64 ? ei[idx * 2] : ei[idx];
}

// ---------------------------------------------------------------------------
// Multi-split pass 1: per-block bucket histogram (LDS), dense write-out.
// ---------------------------------------------------------------------------
__global__ __launch_bounds__(256) void hist_kernel(
        const int* __restrict__ ei, const int* __restrict__ flag,
        long long E, long long E2, int* __restrict__ hist, int K2, int EPB) {
    __shared__ int hcnt[KBUKMAX];
    const int is64 = *flag;
    const int t = threadIdx.x;
    if (t < K2) hcnt[t] = 0;
    __syncthreads();
    const long long lo = (long long)blockIdx.x * EPB;
    const long long hi = min(E2, lo + EPB);
    for (long long e = lo + t; e < hi; e += 256) {
        int d = (e < E) ? edge_val(ei, E + e, is64) : (int)(e - E);
        atomicAdd(&hcnt[d >> BKT_SHIFT], 1);
    }
    __syncthreads();
    if (t < K2) hist[t * gridDim.x + blockIdx.x] = hcnt[t];
}

// ---------------- generic hierarchical exclusive scan (in-place) ----------
__global__ void scan_ga_kernel(int* __restrict__ a, int* __restrict__ bsum, int L) {
    __shared__ int wsum[4];
    const int t = threadIdx.x;
    const int i0 = blockIdx.x * 1024 + t * 4;
    int v[4]; int s = 0;
    #pragma unroll
    for (int k = 0; k < 4; ++k) {
        v[k] = (i0 + k < L) ? a[i0 + k] : 0;
        s += v[k];
    }
    const int lane = t & 63, wid = t >> 6;
    int incl = s;
    #pragma unroll
    for (int d = 1; d < 64; d <<= 1) {
        int u = __shfl_up(incl, d);
        if (lane >= d) incl += u;
    }
    if (lane == 63) wsum[wid] = incl;
    __syncthreads();
    int woff = 0;
    for (int w = 0; w < wid; ++w) woff += wsum[w];
    int excl = woff + incl - s;
    #pragma unroll
    for (int k = 0; k < 4; ++k) {
        if (i0 + k < L) a[i0 + k] = excl;
        excl += v[k];
    }
    if (t == 255) bsum[blockIdx.x] = woff + incl;
}

__global__ __launch_bounds__(1024) void scan_flat_kernel(int* __restrict__ a, int L) {
    __shared__ int wsum[16];
    __shared__ int carry_s;
    const int t = threadIdx.x;
    const int lane = t & 63, wid = t >> 6;
    if (t == 0) carry_s = 0;
    __syncthreads();
    for (int start = 0; start < L; start += 1024) {
        int idx = start + t;
        int v = (idx < L) ? a[idx] : 0;
        int incl = v;
        #pragma unroll
        for (int d = 1; d < 64; d <<= 1) {
            int u = __shfl_up(incl, d);
            if (lane >= d) incl += u;
        }
        if (lane == 63) wsum[wid] = incl;
        __syncthreads();
        int woff = 0;
        for (int w = 0; w < wid; ++w) woff += wsum[w];
        int carry = carry_s;
        __syncthreads();
        if (idx < L) a[idx] = carry + woff + incl - v;
        if (t == 1023) carry_s = carry + woff + incl;
        __syncthreads();
    }
}

__global__ void scan_gc_kernel(int* __restrict__ a, const int* __restrict__ bsum, int L) {
    int idx = blockIdx.x * blockDim.x + threadIdx.x;
    if (idx < L) a[idx] += bsum[idx >> 10];
}

// ---------------------------------------------------------------------------
// Multi-split pass 2: scatter packed (src | dlow<<17) into bins.
// ---------------------------------------------------------------------------
__global__ __launch_bounds__(256) void scatter_kernel(
        const int* __restrict__ ei, const int* __restrict__ flag,
        long long E, long long E2, const int* __restrict__ off,
        unsigned* __restrict__ bins, int K2, int EPB) {
    __shared__ int cur[KBUKMAX];
    const int is64 = *flag;
    const int t = threadIdx.x;
    if (t < K2) cur[t] = off[t * gridDim.x + blockIdx.x];
    __syncthreads();
    const long long lo = (long long)blockIdx.x * EPB;
    const long long hi = min(E2, lo + EPB);
    for (long long e = lo + t; e < hi; e += 256) {
        int s, d;
        if (e < E) { s = edge_val(ei, e, is64); d = edge_val(ei, E + e, is64); }
        else       { s = d = (int)(e - E); }
        int b = d >> BKT_SHIFT;
        int pos = atomicAdd(&cur[b], 1);
        bins[pos] = (unsigned)s | ((unsigned)(d & (NPB - 1)) << 17);
    }
}

// ---------------------------------------------------------------------------
// Fused CSR build, one block per 512-node bucket (bucket's CSR window ==
// its bins window, so rowptr = bucket_base + local excl scan).
// ---------------------------------------------------------------------------
__global__ __launch_bounds__(512) void csr_b_kernel(
        const unsigned* __restrict__ bins, const int* __restrict__ off,
        int* __restrict__ rowptr, float* __restrict__ dis, int* __restrict__ csr_src,
        int N, int K2, long long E2) {
    __shared__ int lcur[NPB];
    __shared__ int wsum[8];
    const int b = blockIdx.x, t = threadIdx.x;     // 512 threads
    const int nbase = b << BKT_SHIFT;
    const int nn = min(NPB, N - nbase);
    lcur[t] = 0;
    __syncthreads();
    const int base = off[b * NBLK_BIN];
    const int end  = (b == K2 - 1) ? (int)E2 : off[(b + 1) * NBLK_BIN];
    for (int i = base + t; i < end; i += 512)
        atomicAdd(&lcur[bins[i] >> 17], 1);
    __syncthreads();
    const int lane = t & 63, wid = t >> 6;
    int v = lcur[t];
    int incl = v;
    #pragma unroll
    for (int d = 1; d < 64; d <<= 1) {
        int u = __shfl_up(incl, d);
        if (lane >= d) incl += u;
    }
    if (lane == 63) wsum[wid] = incl;
    __syncthreads();
    int woff = 0;
    for (int w = 0; w < wid; ++w) woff += wsum[w];
    int excl = woff + incl - v;
    if (t < nn) {
        rowptr[nbase + t] = base + excl;
        dis[nbase + t] = rsqrtf((float)v);         // deg >= 1 (self-loop)
    }
    __syncthreads();
    lcur[t] = base + excl;
    __syncthreads();
    for (int i = base + t; i < end; i += 512) {
        unsigned u = bins[i];
        int pos = atomicAdd(&lcur[u >> 17], 1);
        csr_src[pos] = (int)(u & 0x1FFFFu);
    }
    if (b == 0 && t == 0) rowptr[N] = (int)E2;
}

// ---------------------------------------------------------------------------
// gemm1: register-tiled, fp16 output table. hws_h[i] = fp16(dis[i]*(x[i]@W1)).
// ---------------------------------------------------------------------------
__global__ __launch_bounds__(256) void gemm1_kernel(
        const float* __restrict__ x, const float* __restrict__ W1,
        const float* __restrict__ dis, _Float16* __restrict__ hws_h, int N) {
    __shared__ float sWt[D_HID][D_IN + 4];         // transposed, +4 pad
    const int t = threadIdx.x;
    for (int i = t; i < D_IN * D_HID; i += 256) {
        int k = i >> 5, c = i & 31;
        sWt[c][k] = W1[i];
    }
    __syncthreads();
    const int c_t = t & 7;                         // 8 col-groups of 4
    const int r_t = t >> 3;                        // 32 row-threads of 4
    const long long row0 = (long long)blockIdx.x * 128 + (long long)r_t * 4;
    const float4* x4 = (const float4*)x;
    float acc[4][4];
    #pragma unroll
    for (int i = 0; i < 4; ++i)
        #pragma unroll
        for (int j = 0; j < 4; ++j) acc[i][j] = 0.f;
    long long r[4]; bool val[4];
    #pragma unroll
    for (int i = 0; i < 4; ++i) {
        long long rr = row0 + i;
        val[i] = rr < N;
        r[i] = val[i] ? rr : (long long)(N - 1);
    }
    #pragma unroll 4
    for (int q = 0; q < 32; ++q) {
        float4 wv[4];
        #pragma unroll
        for (int j = 0; j < 4; ++j)
            wv[j] = *(const float4*)&sWt[c_t * 4 + j][q * 4];
        #pragma unroll
        for (int i = 0; i < 4; ++i) {
            float4 xv = x4[r[i] * 32 + q];
            #pragma unroll
            for (int j = 0; j < 4; ++j) {
                acc[i][j] = fmaf(xv.x, wv[j].x, acc[i][j]);
                acc[i][j] = fmaf(xv.y, wv[j].y, acc[i][j]);
                acc[i][j] = fmaf(xv.z, wv[j].z, acc[i][j]);
                acc[i][j] = fmaf(xv.w, wv[j].w, acc[i][j]);
            }
        }
    }
    half4* hh4 = (half4*)hws_h;
    #pragma unroll
    for (int i = 0; i < 4; ++i) {
        if (val[i]) {
            float dd = dis[r[i]];
            half4 o;
            o.x = (_Float16)(acc[i][0] * dd); o.y = (_Float16)(acc[i][1] * dd);
            o.z = (_Float16)(acc[i][2] * dd); o.w = (_Float16)(acc[i][3] * dd);
            hh4[r[i] * 8 + c_t] = o;
        }
    }
}

// ---------------------------------------------------------------------------
// GCN aggregate + bias + ReLU. 8 edges in flight per wave; fp16 gather (8B
// per lane), f32 accumulate. h1 stays f32 (linear-read input of gemm2).
// ---------------------------------------------------------------------------
__global__ void gcn_agg_kernel(const int* __restrict__ rowptr, const int* __restrict__ csr_src,
                               const _Float16* __restrict__ hws_h, const float* __restrict__ dis,
                               const float* __restrict__ b1, float* __restrict__ h1, int N) {
    const int lane = threadIdx.x & 63;
    const int u = lane & 7, grp = lane >> 3;       // 8 groups x 8 lanes
    const int wib = threadIdx.x >> 6;              // 4 waves / block
    const half4* hh4 = (const half4*)hws_h;
    float4* h14 = (float4*)h1;
    const float4 b14 = ((const float4*)b1)[u];
    for (int i = blockIdx.x * 4 + wib; i < N; i += gridDim.x * 4) {
        const int b = rowptr[i], e = rowptr[i + 1];
        float ax = 0.f, ay = 0.f, az = 0.f, aw = 0.f;
        for (int j = b + grp; j < e; j += 8) {
            int s = csr_src[j];
            half4 hv = hh4[s * 8 + u];
            ax += (float)hv.x; ay += (float)hv.y;
            az += (float)hv.z; aw += (float)hv.w;
        }
        #pragma unroll
        for (int d = 8; d <= 32; d <<= 1) {
            ax += __shfl_xor(ax, d); ay += __shfl_xor(ay, d);
            az += __shfl_xor(az, d); aw += __shfl_xor(aw, d);
        }
        if (grp == 0) {
            float dd = dis[i];
            float4 o;
            o.x = fmaf(dd, ax, b14.x); o.y = fmaf(dd, ay, b14.y);
            o.z = fmaf(dd, az, b14.z); o.w = fmaf(dd, aw, b14.w);
            o.x = o.x > 0.f ? o.x : 0.f; o.y = o.y > 0.f ? o.y : 0.f;
            o.z = o.z > 0.f ? o.z : 0.f; o.w = o.w > 0.f ? o.w : 0.f;
            h14[(long long)i * 8 + u] = o;
        }
    }
}

// g_h = fp16(h1 @ W2) ; a_s/a_d computed from f32 values (full precision)
__global__ void gemm2_kernel(const float* __restrict__ h1, const float* __restrict__ W2,
                             const float* __restrict__ att_s, const float* __restrict__ att_d,
                             _Float16* __restrict__ g_h, float* __restrict__ a_s,
                             float* __restrict__ a_d, int N) {
    __shared__ float sW[D_HID * D_OUT];
    __shared__ float sas[D_OUT], sad[D_OUT];
    __shared__ float sh[8][D_HID];
    const int t = threadIdx.x;              // 256
    const int c = t & 31, r = t >> 5;
    for (int i = t; i < D_HID * D_OUT; i += 256) sW[i] = W2[i];
    if (t < D_OUT) { sas[t] = att_s[t]; sad[t] = att_d[t]; }
    for (long long base = (long long)blockIdx.x * 8; base < N; base += (long long)gridDim.x * 8) {
        __syncthreads();
        if (base * D_HID + t < (long long)N * D_HID) sh[r][c] = h1[base * D_HID + t];
        __syncthreads();
        long long row = base + r;
        if (row < N) {
            float gv = 0.0f;
            #pragma unroll
            for (int k = 0; k < D_HID; ++k) gv = fmaf(sh[r][k], sW[k * D_OUT + c], gv);
            g_h[row * D_OUT + c] = (_Float16)gv;
            float ps = gv * sas[c];
            float pd = gv * sad[c];
            #pragma unroll
            for (int d = 16; d >= 1; d >>= 1) {
                ps += __shfl_xor(ps, d);
                pd += __shfl_xor(pd, d);
            }
            if (c == 0) { a_s[row] = ps; a_d[row] = pd; }
        }
    }
}

// ---------------------------------------------------------------------------
// GAT aggregate, online segment-softmax, 8 edges in flight, fp16 gather.
// ---------------------------------------------------------------------------
__global__ void gat_agg_kernel(const int* __restrict__ rowptr, const int* __restrict__ csr_src,
                               const _Float16* __restrict__ g_h, const float* __restrict__ a_s,
                               const float* __restrict__ a_d, const float* __restrict__ b2,
                               float* __restrict__ out, int N) {
    const int lane = threadIdx.x & 63;
    const int u = lane & 7, grp = lane >> 3;       // 8 groups x 8 lanes
    const int wib = threadIdx.x >> 6;
    const half4* gh4 = (const half4*)g_h;
    float4* out4 = (float4*)out;
    const float4 b24 = ((const float4*)b2)[u];
    for (int i = blockIdx.x * 4 + wib; i < N; i += gridDim.x * 4) {
        const int b = rowptr[i], e = rowptr[i + 1];
        const float adi = a_d[i];
        float m = -1e30f, ssum = 0.f;
        float ax = 0.f, ay = 0.f, az = 0.f, aw = 0.f;
        for (int j = b + grp; j < e; j += 8) {
            int s = csr_src[j];
            float ev = a_s[s] + adi;
            ev = ev > 0.f ? ev : NEG_SLOPE * ev;
            float mn = fmaxf(m, ev);
            float scale = __expf(m - mn);
            float w = __expf(ev - mn);
            half4 gv = gh4[s * 8 + u];
            ssum = ssum * scale + w;
            ax = fmaf(ax, scale, w * (float)gv.x);
            ay = fmaf(ay, scale, w * (float)gv.y);
            az = fmaf(az, scale, w * (float)gv.z);
            aw = fmaf(aw, scale, w * (float)gv.w);
            m = mn;
        }
        #pragma unroll
        for (int d = 8; d <= 32; d <<= 1) {
            float mo = __shfl_xor(m, d);
            float so = __shfl_xor(ssum, d);
            float ox = __shfl_xor(ax, d), oy = __shfl_xor(ay, d);
            float oz = __shfl_xor(az, d), ow = __shfl_xor(aw, d);
            float M = fmaxf(m, mo);
            float e0 = __expf(m - M), e1 = __expf(mo - M);
            ssum = ssum * e0 + so * e1;
            ax = ax * e0 + ox * e1; ay = ay * e0 + oy * e1;
            az = az * e0 + oz * e1; aw = aw * e0 + ow * e1;
            m = M;
        }
        if (grp == 0) {
            float inv = 1.f / (ssum + EPS_F);
            float4 o;
            o.x = fmaf(ax, inv, b24.x); o.y = fmaf(ay, inv, b24.y);
            o.z = fmaf(az, inv, b24.z); o.w = fmaf(aw, inv, b24.w);
            out4[(long long)i * 8 + u] = o;
        }
    }
}

extern "C" void kernel_launch(void* const* d_in, const int* in_sizes, int n_in,
                              void* d_out, int out_size, void* d_ws, size_t ws_size,
                              hipStream_t stream) {
    const float* x       = (const float*)d_in[0];
    const int*   ei      = (const int*)d_in[1];   // int32 or int64, detected on device
    const float* W1      = (const float*)d_in[2];
    const float* b1      = (const float*)d_in[3];
    const float* W2      = (const float*)d_in[4];
    const float* att_src = (const float*)d_in[5];
    const float* att_dst = (const float*)d_in[6];
    const float* b2      = (const float*)d_in[7];
    float* out = (float*)d_out;

    const long long N  = in_sizes[0] / D_IN;
    const long long E  = in_sizes[1] / 2;
    const long long E2 = E + N;
    const int K2  = (int)((N + NPB - 1) >> BKT_SHIFT);              // 196 for N=100K
    const int EPB = (int)((E2 + NBLK_BIN - 1) / NBLK_BIN);
    const int LH  = K2 * NBLK_BIN;
    const int NBH = (LH + 1023) / 1024;

    // workspace layout (256B aligned slices)
    char* ws = (char*)d_ws;
    size_t off0 = 0;
    auto alloc = [&](size_t bytes) -> void* {
        off0 = (off0 + 255) & ~(size_t)255;
        void* p = ws + off0;
        off0 += bytes;
        return p;
    };
    int*   flag     = (int*)  alloc(16);
    int*   hist     = (int*)  alloc((size_t)KBUKMAX * NBLK_BIN * 4);
    unsigned* bins  = (unsigned*)alloc((size_t)E2 * 4);
    int*   rowptr   = (int*)  alloc((size_t)(N + 1) * 4);
    int*   csr_src  = (int*)  alloc((size_t)E2 * 4);
    float* dis      = (float*)alloc((size_t)N * 4);
    _Float16* hws_h = (_Float16*)alloc((size_t)N * D_HID * 2);
    float* h1       = (float*)alloc((size_t)N * D_HID * 4);
    _Float16* g_h   = (_Float16*)alloc((size_t)N * D_OUT * 2);
    float* as       = (float*)alloc((size_t)N * 4);
    float* ad       = (float*)alloc((size_t)N * 4);
    int*   bsum     = (int*)  alloc((size_t)NBH * 4);
    (void)ws_size; (void)n_in; (void)out_size;

    detect_kernel<<<1, 64, 0, stream>>>(ei, E, flag);
    hist_kernel<<<NBLK_BIN, 256, 0, stream>>>(ei, flag, E, E2, hist, K2, EPB);
    scan_ga_kernel<<<NBH, 256, 0, stream>>>(hist, bsum, LH);
    scan_flat_kernel<<<1, 1024, 0, stream>>>(bsum, NBH);
    scan_gc_kernel<<<(LH + 255) / 256, 256, 0, stream>>>(hist, bsum, LH);
    scatter_kernel<<<NBLK_BIN, 256, 0, stream>>>(ei, flag, E, E2, hist, bins, K2, EPB);
    csr_b_kernel<<<K2, 512, 0, stream>>>(bins, hist, rowptr, dis, csr_src, (int)N, K2, E2);
    gemm1_kernel<<<(int)((N + 127) / 128), 256, 0, stream>>>(x, W1, dis, hws_h, (int)N);
    int agg_blocks = (int)((N + 3) / 4);
    gcn_agg_kernel<<<agg_blocks, 256, 0, stream>>>(rowptr, csr_src, hws_h, dis, b1, h1, (int)N);
    gemm2_kernel<<<1024, 256, 0, stream>>>(h1, W2, att_src, att_dst, g_h, as, ad, (int)N);
    gat_agg_kernel<<<agg_blocks, 256, 0, stream>>>(rowptr, csr_src, g_h, as, ad, b2, out, (int)N);
}